// Round 11
// baseline (785.914 us; speedup 1.0000x reference)
//
#include <hip/hip_runtime.h>
#include <hip/hip_bf16.h>
#include <hip/hip_cooperative_groups.h>

namespace cg = cooperative_groups;

#define D 128
#define EPSV 1e-5f

static inline int cdiv(int a, int b) { return (a + b - 1) / b; }

// bf16 RNE pack
__device__ __forceinline__ unsigned short f2bf(float f) {
    unsigned int x = __float_as_uint(f);
    unsigned int r = x + 0x7fffu + ((x >> 16) & 1u);
    return (unsigned short)(r >> 16);
}

// ---------------- cooperative preprocessing megakernel ----------------
// One dispatch replaces: memset, hist, scan x2, scatter, sort+deg, fill_w,
// bn_stats(layer1), bn_reduce(layer1). 512 blocks x 256 threads (2/CU,
// co-resident), grid.sync() between phases. All phases deterministic.

__global__ __launch_bounds__(256) void prep_coop(
    const int* __restrict__ row, const int* __restrict__ col, const float* __restrict__ ea,
    const int* __restrict__ xidx, const float* __restrict__ emb,
    const float* __restrict__ gamma1, const float* __restrict__ beta1,
    int* __restrict__ cnt, int* __restrict__ bsum, int* __restrict__ offs,
    int* __restrict__ cursor, long long* __restrict__ pk, int2* __restrict__ csr,
    float* __restrict__ dis, float* __restrict__ pS, float* __restrict__ pQ,
    float* __restrict__ scale1, float* __restrict__ shift1, int N, int E) {
    cg::grid_group grid = cg::this_grid();
    int tid = threadIdx.x;
    int bid = blockIdx.x;
    int nblk = gridDim.x;            // 512
    int gsize = nblk * 256;
    int gid = bid * 256 + tid;
    __shared__ int sm_i[256];
    __shared__ float4 redA[256], redB[256];

    // ---- P0: zero cnt ----
    for (int i = gid; i < N; i += gsize) cnt[i] = 0;
    if (gid == 0) offs[N] = E;
    grid.sync();

    // ---- P1: histogram + layer-1 BN partials ----
    for (int e = gid; e < E; e += gsize) atomicAdd(&cnt[col[e]], 1);
    {
        int sub = tid >> 5, q = tid & 31;
        float4 s = make_float4(0, 0, 0, 0), s2 = make_float4(0, 0, 0, 0);
        int stride = nblk * 8;
        for (int i = bid * 8 + sub; i < N; i += stride) {
            int r = xidx[i];
            float4 v = *(const float4*)&emb[(long)r * D + q * 4];
            s.x += v.x; s.y += v.y; s.z += v.z; s.w += v.w;
            s2.x += v.x * v.x; s2.y += v.y * v.y; s2.z += v.z * v.z; s2.w += v.w * v.w;
        }
        redA[tid] = s;
        redB[tid] = s2;
        __syncthreads();
        for (int off = 128; off >= 32; off >>= 1) {
            if (tid < off) {
                float4 a = redA[tid + off], b = redB[tid + off];
                redA[tid].x += a.x; redA[tid].y += a.y; redA[tid].z += a.z; redA[tid].w += a.w;
                redB[tid].x += b.x; redB[tid].y += b.y; redB[tid].z += b.z; redB[tid].w += b.w;
            }
            __syncthreads();
        }
        if (tid < 32) {
            float4 a = redA[tid], b = redB[tid];
            pS[(q * 4 + 0) * nblk + bid] = a.x;
            pS[(q * 4 + 1) * nblk + bid] = a.y;
            pS[(q * 4 + 2) * nblk + bid] = a.z;
            pS[(q * 4 + 3) * nblk + bid] = a.w;
            pQ[(q * 4 + 0) * nblk + bid] = b.x;
            pQ[(q * 4 + 1) * nblk + bid] = b.y;
            pQ[(q * 4 + 2) * nblk + bid] = b.z;
            pQ[(q * 4 + 3) * nblk + bid] = b.w;
        }
    }
    grid.sync();

    // ---- P2: chunk sums (blocks < nch) | layer-1 BN reduce (next 128 blocks) ----
    int nch = (N + 255) >> 8;  // 196 for N=50000 (must be <= 256)
    if (bid < nch) {
        int i = bid * 256 + tid;
        sm_i[tid] = (i < N) ? cnt[i] : 0;
        __syncthreads();
        for (int off = 128; off > 0; off >>= 1) {
            if (tid < off) sm_i[tid] += sm_i[tid + off];
            __syncthreads();
        }
        if (tid == 0) bsum[bid] = sm_i[0];
    } else if (bid - nch < D) {
        int d = bid - nch;
        float s = pS[d * nblk + tid] + pS[d * nblk + tid + 256];
        float q = pQ[d * nblk + tid] + pQ[d * nblk + tid + 256];
        redA[tid].x = s;
        redB[tid].x = q;
        __syncthreads();
        for (int off = 128; off > 0; off >>= 1) {
            if (tid < off) {
                redA[tid].x += redA[tid + off].x;
                redB[tid].x += redB[tid + off].x;
            }
            __syncthreads();
        }
        if (tid == 0) {
            float mean = redA[0].x / (float)N;
            float var = redB[0].x / (float)N - mean * mean;
            float rstd = rsqrtf(var + EPSV);
            float sc = gamma1[d] * rstd;
            scale1[d] = sc;
            shift1[d] = beta1[d] - mean * sc;
        }
    }
    grid.sync();

    // ---- P3: block 0 exclusive-scans bsum[0..nch) ----
    if (bid == 0) {
        int v = (tid < nch) ? bsum[tid] : 0;
        sm_i[tid] = v;
        __syncthreads();
        for (int off = 1; off < 256; off <<= 1) {
            int t = (tid >= off) ? sm_i[tid - off] : 0;
            __syncthreads();
            sm_i[tid] += t;
            __syncthreads();
        }
        if (tid < nch) bsum[tid] = sm_i[tid] - v;
    }
    grid.sync();

    // ---- P4: per-chunk exclusive scan -> offs, cursor ----
    if (bid < nch) {
        int i = bid * 256 + tid;
        int v = (i < N) ? cnt[i] : 0;
        sm_i[tid] = v;
        __syncthreads();
        for (int off = 1; off < 256; off <<= 1) {
            int t = (tid >= off) ? sm_i[tid - off] : 0;
            __syncthreads();
            sm_i[tid] += t;
            __syncthreads();
        }
        if (i < N) {
            int excl = sm_i[tid] - v + bsum[bid];
            offs[i] = excl;
            cursor[i] = excl;
        }
    }
    grid.sync();

    // ---- P5: scatter packed (edge_id<<32 | src_row) ----
    for (int e = gid; e < E; e += gsize) {
        int c = col[e];
        int r = row[e];
        int p = atomicAdd(&cursor[c], 1);
        pk[p] = ((long long)e << 32) | (unsigned int)r;
    }
    grid.sync();

    // ---- P6: wave-level bitonic sort per node; csr=(r, ea); deg -> dis ----
    int lane = tid & 63, wv = tid >> 6;
    for (int node = bid * 4 + wv; node < N; node += nblk * 4) {
        int p0 = offs[node], p1 = offs[node + 1];
        int deg = p1 - p0;
        if (deg <= 64) {
            long long v = (lane < deg) ? pk[p0 + lane] : 0x7fffffffffffffffLL;
            for (int k = 2; k <= 64; k <<= 1) {
                for (int j = k >> 1; j > 0; j >>= 1) {
                    long long partner = __shfl_xor(v, j, 64);
                    bool up = ((lane & k) == 0);
                    bool keepMin = ((lane & j) == 0);
                    long long mn = v < partner ? v : partner;
                    long long mx = v < partner ? partner : v;
                    v = (up == keepMin) ? mn : mx;
                }
            }
            int e = (int)(v >> 32);
            int r = (int)(v & 0xffffffffLL);
            float av = (lane < deg) ? ea[e] : 0.f;
            if (lane < deg) csr[p0 + lane] = make_int2(r, __float_as_int(av));
            float s = av;
            for (int off = 32; off > 0; off >>= 1) s += __shfl_xor(s, off, 64);
            if (lane == 0) dis[node] = s > 0.f ? rsqrtf(fmaxf(s, EPSV)) : 0.f;
        } else if (lane == 0) {  // deterministic O(d^2) selection fallback (unreachable)
            float dg = 0.f;
            for (int p = p0; p < p1; ++p) {
                long long best = 0x7fffffffffffffffLL;
                for (int q2 = p0; q2 < p1; ++q2) {
                    long long cand = pk[q2];
                    int less = 0;
                    for (int q3 = p0; q3 < p1; ++q3)
                        if (pk[q3] < cand) ++less;
                    if (less == p - p0) { best = cand; break; }
                }
                int e = (int)(best >> 32);
                int r = (int)(best & 0xffffffffLL);
                float av = ea[e];
                csr[p] = make_int2(r, __float_as_int(av));
                dg += av;
            }
            dis[node] = dg > 0.f ? rsqrtf(fmaxf(dg, EPSV)) : 0.f;
        }
    }
    grid.sync();

    // ---- P7: finalize weights (r, ea) -> (r, dis[r]*ea*dis[c]) ----
    for (int node = bid * 4 + wv; node < N; node += nblk * 4) {
        int p0 = offs[node], p1 = offs[node + 1];
        float dc = dis[node];
        for (int p = p0 + lane; p < p1; p += 64) {
            int2 pr = csr[p];
            float w = dis[pr.x] * __int_as_float(pr.y) * dc;
            csr[p] = make_int2(pr.x, __float_as_int(w));
        }
    }
}

// ---------------- layer-2 BN reduce (partials from agg1) ----------------

__global__ __launch_bounds__(256) void bn_reduce(const float* __restrict__ pS,
                                                 const float* __restrict__ pQ, int nb,
                                                 const float* __restrict__ gamma,
                                                 const float* __restrict__ beta,
                                                 float* __restrict__ scale,
                                                 float* __restrict__ shift, float n) {
    int d = blockIdx.x;
    int tid = threadIdx.x;
    float s = 0.f, q = 0.f;
    for (int b = tid; b < nb; b += 256) {
        s += pS[d * nb + b];
        q += pQ[d * nb + b];
    }
    __shared__ float smS[256], smQ[256];
    smS[tid] = s;
    smQ[tid] = q;
    __syncthreads();
    for (int off = 128; off > 0; off >>= 1) {
        if (tid < off) {
            smS[tid] += smS[tid + off];
            smQ[tid] += smQ[tid + off];
        }
        __syncthreads();
    }
    if (tid == 0) {
        float mean = smS[0] / n;
        float var = smQ[0] / n - mean * mean;
        float rstd = rsqrtf(var + EPSV);
        float sc = gamma[d] * rstd;
        scale[d] = sc;
        shift[d] = beta[d] - mean * sc;
    }
}

// ---------------- GEMM: h = (src*scale+shift) @ W, output bf16 ----------------

template <bool GATHER>
__global__ __launch_bounds__(256) void gemm_bn(const float* __restrict__ src,
                                               const int* __restrict__ idx,
                                               const float* __restrict__ scale,
                                               const float* __restrict__ shift,
                                               const float* __restrict__ W,
                                               unsigned short* __restrict__ outb, int n) {
    __shared__ float xs[64 * 132];  // 33.8 KB
    int tid = threadIdx.x;
    int r0 = blockIdx.x * 64;
    const float4* scale4 = (const float4*)scale;
    const float4* shift4 = (const float4*)shift;
    for (int it = 0; it < 8; ++it) {
        int flat = it * 256 + tid;
        int r = flat >> 5;
        int kq = flat & 31;
        int gr = r0 + r;
        float4 v = make_float4(0.f, 0.f, 0.f, 0.f);
        if (gr < n) {
            int srow = GATHER ? idx[gr] : gr;
            float4 x4 = *(const float4*)&src[(long)srow * D + kq * 4];
            float4 sc = scale4[kq], sh = shift4[kq];
            v = make_float4(x4.x * sc.x + sh.x, x4.y * sc.y + sh.y, x4.z * sc.z + sh.z,
                            x4.w * sc.w + sh.w);
        }
        *(float4*)&xs[r * 132 + kq * 4] = v;
    }
    __syncthreads();
    int cg2 = tid & 31;
    int rg = tid >> 5;
    float acc[8][4];
#pragma unroll
    for (int j = 0; j < 8; ++j)
#pragma unroll
        for (int q = 0; q < 4; ++q) acc[j][q] = 0.f;
    const float4* Wv = (const float4*)W;
#pragma unroll 2
    for (int k4 = 0; k4 < 128; k4 += 4) {
        float4 wv0 = Wv[(k4 + 0) * 32 + cg2];
        float4 wv1 = Wv[(k4 + 1) * 32 + cg2];
        float4 wv2 = Wv[(k4 + 2) * 32 + cg2];
        float4 wv3 = Wv[(k4 + 3) * 32 + cg2];
#pragma unroll
        for (int j = 0; j < 8; ++j) {
            float4 xv = *(const float4*)&xs[(rg * 8 + j) * 132 + k4];
            acc[j][0] += xv.x * wv0.x; acc[j][1] += xv.x * wv0.y;
            acc[j][2] += xv.x * wv0.z; acc[j][3] += xv.x * wv0.w;
            acc[j][0] += xv.y * wv1.x; acc[j][1] += xv.y * wv1.y;
            acc[j][2] += xv.y * wv1.z; acc[j][3] += xv.y * wv1.w;
            acc[j][0] += xv.z * wv2.x; acc[j][1] += xv.z * wv2.y;
            acc[j][2] += xv.z * wv2.z; acc[j][3] += xv.z * wv2.w;
            acc[j][0] += xv.w * wv3.x; acc[j][1] += xv.w * wv3.y;
            acc[j][2] += xv.w * wv3.z; acc[j][3] += xv.w * wv3.w;
        }
    }
#pragma unroll
    for (int j = 0; j < 8; ++j) {
        int gr = r0 + rg * 8 + j;
        if (gr < n) {
            ushort4 o = make_ushort4(f2bf(acc[j][0]), f2bf(acc[j][1]), f2bf(acc[j][2]),
                                     f2bf(acc[j][3]));
            *(ushort4*)&outb[(long)gr * D + cg2 * 4] = o;
        }
    }
}

// ---------------- aggregation (shuffle-csr, 1 mem op/edge) ----------------

template <bool STATS>
__global__ __launch_bounds__(256) void agg_kernel(const unsigned int* __restrict__ hw,
                                                  const int2* __restrict__ csr,
                                                  const int* __restrict__ offs,
                                                  const float2* __restrict__ bias2,
                                                  float2* __restrict__ xout, int n,
                                                  float* __restrict__ pS,
                                                  float* __restrict__ pQ, int NB) {
    int lane = threadIdx.x & 63;
    int wv = threadIdx.x >> 6;
    float2 bs = bias2[lane];
    float2 s = make_float2(0.f, 0.f), s2 = make_float2(0.f, 0.f);
    int nGroups = (n + 3) >> 2;
    for (int grp = blockIdx.x; grp < nGroups; grp += gridDim.x) {
        int node = grp * 4 + wv;
        if (node < n) {
            int p0 = offs[node], p1 = offs[node + 1];
            float2 acc = bs;
            for (int base = p0; base < p1; base += 64) {
                int cnt = p1 - base;
                if (cnt > 64) cnt = 64;
                int2 e = csr[base + (lane < cnt ? lane : cnt - 1)];
                for (int j = 0; j < cnt; j += 4) {
#pragma unroll
                    for (int u = 0; u < 4; ++u) {
                        int jj = j + u;
                        bool ok = jj < cnt;
                        int sel = ok ? jj : 0;
                        int r = __shfl(e.x, sel, 64);
                        float w = ok ? __int_as_float(__shfl(e.y, sel, 64)) : 0.f;
                        unsigned int uu = hw[(long)r * 64 + lane];
                        acc.x += w * __uint_as_float(uu << 16);
                        acc.y += w * __uint_as_float(uu & 0xffff0000u);
                    }
                }
            }
            float2 x = make_float2(fmaxf(acc.x, 0.f), fmaxf(acc.y, 0.f));
            xout[(long)node * 64 + lane] = x;
            if (STATS) {
                s.x += x.x; s.y += x.y;
                s2.x += x.x * x.x; s2.y += x.y * x.y;
            }
        }
    }
    if (STATS) {
        __shared__ float2 smS[256], smQ[256];
        smS[threadIdx.x] = s;
        smQ[threadIdx.x] = s2;
        __syncthreads();
        if (wv == 0) {
            float2 a = smS[lane], q = smQ[lane];
#pragma unroll
            for (int w2 = 1; w2 < 4; ++w2) {
                float2 b = smS[w2 * 64 + lane], c = smQ[w2 * 64 + lane];
                a.x += b.x; a.y += b.y;
                q.x += c.x; q.y += c.y;
            }
            pS[(2 * lane + 0) * NB + blockIdx.x] = a.x;
            pS[(2 * lane + 1) * NB + blockIdx.x] = a.y;
            pQ[(2 * lane + 0) * NB + blockIdx.x] = q.x;
            pQ[(2 * lane + 1) * NB + blockIdx.x] = q.y;
        }
    }
}

// ---------------- softmax pooling (bounds in-block, 1024 threads) ----------------

__global__ __launch_bounds__(1024) void pool_kernel(const float* __restrict__ tfidf,
                                                    const int* __restrict__ batch,
                                                    const float* __restrict__ x,
                                                    float* __restrict__ out, int n) {
    int g = blockIdx.x;
    int tid = threadIdx.x;
    __shared__ int sbounds[2];
    if (tid < 2) {
        int target = g + tid;
        int lo = 0, hi = n;
        while (lo < hi) {
            int mid = (lo + hi) >> 1;
            if (batch[mid] < target) lo = mid + 1;
            else hi = mid;
        }
        sbounds[tid] = lo;
    }
    __syncthreads();
    int s0 = sbounds[0], s1 = sbounds[1];
    int d = tid & 127, sub = tid >> 7;  // 8-way node split
    __shared__ float red[1024];
    float m = -1e30f;
    for (int i = s0 + tid; i < s1; i += 1024) m = fmaxf(m, tfidf[i]);
    red[tid] = m;
    __syncthreads();
    for (int off = 512; off > 0; off >>= 1) {
        if (tid < off) red[tid] = fmaxf(red[tid], red[tid + off]);
        __syncthreads();
    }
    m = red[0];
    __syncthreads();
    float s = 0.f;
    for (int i = s0 + tid; i < s1; i += 1024) s += __expf(tfidf[i] - m);
    red[tid] = s;
    __syncthreads();
    for (int off = 512; off > 0; off >>= 1) {
        if (tid < off) red[tid] += red[tid + off];
        __syncthreads();
    }
    s = red[0];
    __syncthreads();
    float acc = 0.f;
    for (int i = s0 + sub; i < s1; i += 8) acc += __expf(tfidf[i] - m) * x[(long)i * D + d];
    red[tid] = acc;
    __syncthreads();
    if (tid < 128) {
        float a = 0.f;
#pragma unroll
        for (int w = 0; w < 8; ++w) a += red[w * 128 + d];
        out[g * D + d] = (s1 > s0) ? a / s : 0.f;
    }
}

// ---------------- launch ----------------

extern "C" void kernel_launch(void* const* d_in, const int* in_sizes, int n_in, void* d_out,
                              int out_size, void* d_ws, size_t ws_size, hipStream_t stream) {
    const int N = in_sizes[0];
    const int E = in_sizes[4];
    const int G = out_size / D;
    const int AGG_GRID = 2048;

    const int* x_index = (const int*)d_in[0];
    const float* tfidf = (const float*)d_in[1];
    const int* ei_row = (const int*)d_in[2];
    const int* ei_col = ei_row + E;
    const int* batch = (const int*)d_in[3];
    const float* edge_attr = (const float*)d_in[4];
    const float* emb = (const float*)d_in[5];
    const float* gamma1 = (const float*)d_in[6];
    const float* beta1 = (const float*)d_in[7];
    const float* W1 = (const float*)d_in[8];
    const float* b1 = (const float*)d_in[9];
    const float* gamma2 = (const float*)d_in[10];
    const float* beta2 = (const float*)d_in[11];
    const float* W2 = (const float*)d_in[12];
    const float* b2 = (const float*)d_in[13];
    float* out = (float*)d_out;

    // ---- workspace carve (256B aligned) ----
    size_t off = 0;
    char* base = (char*)d_ws;
    auto carve = [&](size_t bytes) -> void* {
        void* p = base + off;
        off = (off + bytes + 255) & ~(size_t)255;
        return p;
    };
    unsigned short* bufA = (unsigned short*)carve((size_t)N * D * 2);  // h (bf16)
    float* bufB = (float*)carve((size_t)N * D * 4);                    // x (layer output)
    long long* pk = (long long*)carve((size_t)E * 8);                  // packed (e, row)
    int2* csr = (int2*)carve((size_t)E * 8);                           // (row, ea) -> (row, w)
    int* cnt = (int*)carve((size_t)N * 4);
    float* dis = (float*)carve((size_t)N * 4);
    int* offs = (int*)carve((size_t)(N + 1) * 4);
    int* cursor = (int*)carve((size_t)N * 4);
    int* bsum = (int*)carve(256 * 4);
    float* scale1 = (float*)carve(D * 4);
    float* shift1 = (float*)carve(D * 4);
    float* scale2 = (float*)carve(D * 4);
    float* shift2 = (float*)carve(D * 4);
    float* pS = (float*)carve((size_t)AGG_GRID * D * 4);
    float* pQ = (float*)carve((size_t)AGG_GRID * D * 4);
    (void)ws_size;
    (void)n_in;

    // ---- 1. cooperative preprocessing (zero/hist/scan/scatter/sort/fill + BN1) ----
    {
        int Nv = N, Ev = E;
        void* args[] = {(void*)&ei_row, (void*)&ei_col, (void*)&edge_attr,
                        (void*)&x_index, (void*)&emb, (void*)&gamma1, (void*)&beta1,
                        (void*)&cnt, (void*)&bsum, (void*)&offs, (void*)&cursor,
                        (void*)&pk, (void*)&csr, (void*)&dis, (void*)&pS, (void*)&pQ,
                        (void*)&scale1, (void*)&shift1, (void*)&Nv, (void*)&Ev};
        hipLaunchCooperativeKernel((void*)prep_coop, dim3(512), dim3(256), args, 0, stream);
    }

    // ---- 2-3. layer 1: gemm + agg (agg fuses layer-2 BN partials) ----
    gemm_bn<true><<<cdiv(N, 64), 256, 0, stream>>>(emb, x_index, scale1, shift1, W1, bufA, N);
    agg_kernel<true><<<AGG_GRID, 256, 0, stream>>>((const unsigned int*)bufA, csr, offs,
                                                   (const float2*)b1, (float2*)bufB, N, pS, pQ,
                                                   AGG_GRID);

    // ---- 4-6. layer 2 ----
    bn_reduce<<<D, 256, 0, stream>>>(pS, pQ, AGG_GRID, gamma2, beta2, scale2, shift2, (float)N);
    gemm_bn<false><<<cdiv(N, 64), 256, 0, stream>>>(bufB, nullptr, scale2, shift2, W2, bufA, N);
    agg_kernel<false><<<cdiv(N, 4), 256, 0, stream>>>((const unsigned int*)bufA, csr, offs,
                                                      (const float2*)b2, (float2*)bufB, N,
                                                      nullptr, nullptr, 0);

    // ---- 7. softmax pooling ----
    pool_kernel<<<G, 1024, 0, stream>>>(tfidf, batch, bufB, out, N);
}

// Round 12
// 350.987 us; speedup vs baseline: 2.2392x; 2.2392x over previous
//
#include <hip/hip_runtime.h>
#include <hip/hip_bf16.h>

#define D 128
#define EPSV 1e-5f

static inline int cdiv(int a, int b) { return (a + b - 1) / b; }

// bf16 RNE pack
__device__ __forceinline__ unsigned short f2bf(float f) {
    unsigned int x = __float_as_uint(f);
    unsigned int r = x + 0x7fffu + ((x >> 16) & 1u);
    return (unsigned short)(r >> 16);
}

// ---------------- edge preprocessing (fully deterministic) ----------------

__global__ void hist_kernel(const int* __restrict__ col, int* __restrict__ cnt, int E_) {
    int e = blockIdx.x * blockDim.x + threadIdx.x;
    if (e >= E_) return;
    atomicAdd(&cnt[col[e]], 1);  // int atomics: result order-independent
}

__global__ void scan_chunk_sums(const int* __restrict__ cnt, int* __restrict__ bsum, int n) {
    __shared__ int sm[1024];
    int i = blockIdx.x * 1024 + threadIdx.x;
    sm[threadIdx.x] = (i < n) ? cnt[i] : 0;
    __syncthreads();
    for (int off = 512; off > 0; off >>= 1) {
        if (threadIdx.x < off) sm[threadIdx.x] += sm[threadIdx.x + off];
        __syncthreads();
    }
    if (threadIdx.x == 0) bsum[blockIdx.x] = sm[0];
}

__global__ void scan_final(const int* __restrict__ cnt, const int* __restrict__ bsum, int nbk,
                           int* __restrict__ offs, int* __restrict__ cursor, int n, int E_) {
    __shared__ int sm[1024];
    __shared__ int sbo;
    int tid = threadIdx.x;
    int bv = (tid < nbk && tid < blockIdx.x) ? bsum[tid] : 0;
    sm[tid] = bv;
    __syncthreads();
    for (int off = 512; off > 0; off >>= 1) {
        if (tid < off) sm[tid] += sm[tid + off];
        __syncthreads();
    }
    if (tid == 0) {
        sbo = sm[0];
        if (blockIdx.x == 0) offs[n] = E_;
    }
    __syncthreads();
    int i = blockIdx.x * 1024 + tid;
    int v = (i < n) ? cnt[i] : 0;
    sm[tid] = v;
    __syncthreads();
    for (int off = 1; off < 1024; off <<= 1) {
        int t = (tid >= off) ? sm[tid - off] : 0;
        __syncthreads();
        sm[tid] += t;
        __syncthreads();
    }
    if (i < n) {
        int excl = sm[tid] - v + sbo;
        offs[i] = excl;
        cursor[i] = excl;
    }
}

// scatter packed (edge_id<<32 | src_row) into CSR slots
__global__ void scatter_pack(const int* __restrict__ row, const int* __restrict__ col,
                             int* __restrict__ cursor, long long* __restrict__ pk, int E_) {
    int e = blockIdx.x * blockDim.x + threadIdx.x;
    if (e >= E_) return;
    int c = col[e];
    int r = row[e];
    int p = atomicAdd(&cursor[c], 1);
    pk[p] = ((long long)e << 32) | (unsigned int)r;
}

// wave-level bitonic sort per node (key = edge id); writes csr=(r, ea),
// deterministic tree-sum for deg -> dis.
__global__ __launch_bounds__(256) void sort_deg_kernel(const long long* __restrict__ pk,
                                                       const int* __restrict__ offs,
                                                       const float* __restrict__ ea,
                                                       float* __restrict__ dis,
                                                       int2* __restrict__ csr, int n) {
    int node = blockIdx.x * 4 + (threadIdx.x >> 6);
    int lane = threadIdx.x & 63;
    if (node >= n) return;
    int p0 = offs[node], p1 = offs[node + 1];
    int deg = p1 - p0;
    if (deg <= 64) {
        long long v = (lane < deg) ? pk[p0 + lane] : 0x7fffffffffffffffLL;
        for (int k = 2; k <= 64; k <<= 1) {
            for (int j = k >> 1; j > 0; j >>= 1) {
                long long partner = __shfl_xor(v, j, 64);
                bool up = ((lane & k) == 0);
                bool keepMin = ((lane & j) == 0);
                long long mn = v < partner ? v : partner;
                long long mx = v < partner ? partner : v;
                v = (up == keepMin) ? mn : mx;
            }
        }
        int e = (int)(v >> 32);
        int r = (int)(v & 0xffffffffLL);
        float av = (lane < deg) ? ea[e] : 0.f;
        if (lane < deg) csr[p0 + lane] = make_int2(r, __float_as_int(av));
        float s = av;
        for (int off = 32; off > 0; off >>= 1) s += __shfl_xor(s, off, 64);
        if (lane == 0) dis[node] = s > 0.f ? rsqrtf(fmaxf(s, EPSV)) : 0.f;
    } else {
        if (lane == 0) {  // deterministic O(d^2) selection fallback (unreachable)
            float dg = 0.f;
            for (int p = p0; p < p1; ++p) {
                long long best = 0x7fffffffffffffffLL;
                for (int q2 = p0; q2 < p1; ++q2) {
                    long long cand = pk[q2];
                    int less = 0;
                    for (int q3 = p0; q3 < p1; ++q3)
                        if (pk[q3] < cand) ++less;
                    if (less == p - p0) { best = cand; break; }
                }
                int e = (int)(best >> 32);
                int r = (int)(best & 0xffffffffLL);
                float av = ea[e];
                csr[p] = make_int2(r, __float_as_int(av));
                dg += av;
            }
            dis[node] = dg > 0.f ? rsqrtf(fmaxf(dg, EPSV)) : 0.f;
        }
    }
}

// finalize weights: (r, ea) -> (r, dis[r]*ea*dis[c])
__global__ __launch_bounds__(256) void fill_w_kernel(const int* __restrict__ offs,
                                                     const float* __restrict__ dis,
                                                     int2* __restrict__ csr, int n) {
    int node = blockIdx.x * 4 + (threadIdx.x >> 6);
    int lane = threadIdx.x & 63;
    if (node >= n) return;
    int p0 = offs[node], p1 = offs[node + 1];
    float dc = dis[node];
    for (int p = p0 + lane; p < p1; p += 64) {
        int2 pr = csr[p];
        float w = dis[pr.x] * __int_as_float(pr.y) * dc;
        csr[p] = make_int2(pr.x, __float_as_int(w));
    }
}

// ---------------- batch norm stats (layer 1: emb gather) ----------------

template <bool GATHER>
__global__ __launch_bounds__(256) void bn_stats(const float* __restrict__ src,
                                                const int* __restrict__ idx,
                                                float* __restrict__ pS,
                                                float* __restrict__ pQ, int n, int NB) {
    int sub = threadIdx.x >> 5;
    int q = threadIdx.x & 31;
    float4 s = make_float4(0, 0, 0, 0), s2 = make_float4(0, 0, 0, 0);
    int stride = gridDim.x * 8;
    int i = blockIdx.x * 8 + sub;
    int r_next = (i < n) ? (GATHER ? idx[i] : i) : 0;
    for (; i < n; i += stride) {
        int r = r_next;
        int i2 = i + stride;
        if (i2 < n) r_next = GATHER ? idx[i2] : i2;
        float4 v = *(const float4*)&src[(long)r * D + q * 4];
        s.x += v.x; s.y += v.y; s.z += v.z; s.w += v.w;
        s2.x += v.x * v.x; s2.y += v.y * v.y; s2.z += v.z * v.z; s2.w += v.w * v.w;
    }
    __shared__ float4 redA[256], redB[256];
    redA[threadIdx.x] = s;
    redB[threadIdx.x] = s2;
    __syncthreads();
    for (int off = 128; off >= 32; off >>= 1) {
        if (threadIdx.x < off) {
            float4 a = redA[threadIdx.x + off], b = redB[threadIdx.x + off];
            redA[threadIdx.x].x += a.x; redA[threadIdx.x].y += a.y;
            redA[threadIdx.x].z += a.z; redA[threadIdx.x].w += a.w;
            redB[threadIdx.x].x += b.x; redB[threadIdx.x].y += b.y;
            redB[threadIdx.x].z += b.z; redB[threadIdx.x].w += b.w;
        }
        __syncthreads();
    }
    if (threadIdx.x < 32) {
        float4 a = redA[threadIdx.x], b = redB[threadIdx.x];
        int bofs = blockIdx.x;
        pS[(q * 4 + 0) * NB + bofs] = a.x;
        pS[(q * 4 + 1) * NB + bofs] = a.y;
        pS[(q * 4 + 2) * NB + bofs] = a.z;
        pS[(q * 4 + 3) * NB + bofs] = a.w;
        pQ[(q * 4 + 0) * NB + bofs] = b.x;
        pQ[(q * 4 + 1) * NB + bofs] = b.y;
        pQ[(q * 4 + 2) * NB + bofs] = b.z;
        pQ[(q * 4 + 3) * NB + bofs] = b.w;
    }
}

__global__ __launch_bounds__(256) void bn_reduce(const float* __restrict__ pS,
                                                 const float* __restrict__ pQ, int nb,
                                                 const float* __restrict__ gamma,
                                                 const float* __restrict__ beta,
                                                 float* __restrict__ scale,
                                                 float* __restrict__ shift, float n) {
    int d = blockIdx.x;
    int tid = threadIdx.x;
    float s = 0.f, q = 0.f;
    for (int b = tid; b < nb; b += 256) {
        s += pS[d * nb + b];
        q += pQ[d * nb + b];
    }
    __shared__ float smS[256], smQ[256];
    smS[tid] = s;
    smQ[tid] = q;
    __syncthreads();
    for (int off = 128; off > 0; off >>= 1) {
        if (tid < off) {
            smS[tid] += smS[tid + off];
            smQ[tid] += smQ[tid + off];
        }
        __syncthreads();
    }
    if (tid == 0) {
        float mean = smS[0] / n;
        float var = smQ[0] / n - mean * mean;
        float rstd = rsqrtf(var + EPSV);
        float sc = gamma[d] * rstd;
        scale[d] = sc;
        shift[d] = beta[d] - mean * sc;
    }
}

// ---------------- GEMM: h = (src*scale+shift) @ W, output bf16 ----------------

template <bool GATHER>
__global__ __launch_bounds__(256) void gemm_bn(const float* __restrict__ src,
                                               const int* __restrict__ idx,
                                               const float* __restrict__ scale,
                                               const float* __restrict__ shift,
                                               const float* __restrict__ W,
                                               unsigned short* __restrict__ outb, int n) {
    __shared__ float xs[64 * 132];  // 33.8 KB
    int tid = threadIdx.x;
    int r0 = blockIdx.x * 64;
    const float4* scale4 = (const float4*)scale;
    const float4* shift4 = (const float4*)shift;
    for (int it = 0; it < 8; ++it) {
        int flat = it * 256 + tid;
        int r = flat >> 5;
        int kq = flat & 31;
        int gr = r0 + r;
        float4 v = make_float4(0.f, 0.f, 0.f, 0.f);
        if (gr < n) {
            int srow = GATHER ? idx[gr] : gr;
            float4 x4 = *(const float4*)&src[(long)srow * D + kq * 4];
            float4 sc = scale4[kq], sh = shift4[kq];
            v = make_float4(x4.x * sc.x + sh.x, x4.y * sc.y + sh.y, x4.z * sc.z + sh.z,
                            x4.w * sc.w + sh.w);
        }
        *(float4*)&xs[r * 132 + kq * 4] = v;
    }
    __syncthreads();
    int cg = tid & 31;
    int rg = tid >> 5;
    float acc[8][4];
#pragma unroll
    for (int j = 0; j < 8; ++j)
#pragma unroll
        for (int q = 0; q < 4; ++q) acc[j][q] = 0.f;
    const float4* Wv = (const float4*)W;
#pragma unroll 2
    for (int k4 = 0; k4 < 128; k4 += 4) {
        float4 wv0 = Wv[(k4 + 0) * 32 + cg];
        float4 wv1 = Wv[(k4 + 1) * 32 + cg];
        float4 wv2 = Wv[(k4 + 2) * 32 + cg];
        float4 wv3 = Wv[(k4 + 3) * 32 + cg];
#pragma unroll
        for (int j = 0; j < 8; ++j) {
            float4 xv = *(const float4*)&xs[(rg * 8 + j) * 132 + k4];
            acc[j][0] += xv.x * wv0.x; acc[j][1] += xv.x * wv0.y;
            acc[j][2] += xv.x * wv0.z; acc[j][3] += xv.x * wv0.w;
            acc[j][0] += xv.y * wv1.x; acc[j][1] += xv.y * wv1.y;
            acc[j][2] += xv.y * wv1.z; acc[j][3] += xv.y * wv1.w;
            acc[j][0] += xv.z * wv2.x; acc[j][1] += xv.z * wv2.y;
            acc[j][2] += xv.z * wv2.z; acc[j][3] += xv.z * wv2.w;
            acc[j][0] += xv.w * wv3.x; acc[j][1] += xv.w * wv3.y;
            acc[j][2] += xv.w * wv3.z; acc[j][3] += xv.w * wv3.w;
        }
    }
#pragma unroll
    for (int j = 0; j < 8; ++j) {
        int gr = r0 + rg * 8 + j;
        if (gr < n) {
            ushort4 o = make_ushort4(f2bf(acc[j][0]), f2bf(acc[j][1]), f2bf(acc[j][2]),
                                     f2bf(acc[j][3]));
            *(ushort4*)&outb[(long)gr * D + cg * 4] = o;
        }
    }
}

// ---------------- aggregation: dual-edge gathers ----------------
// bf16 h rows (256B). Wave splits into two 32-lane halves: half h processes
// edges j+h; each lane loads uint2 (8B = 4 features). One gather instruction
// covers TWO edges -> half the issue slots of R10. (r,w) via __shfl from the
// wave's coalesced csr chunk (1 csr load per 64 edges). Halves combine with
// 4 shfl_xor(32); lanes 0-31 write the float4 output row. STATS variant
// accumulates next layer's BN partials.

template <bool STATS>
__global__ __launch_bounds__(256) void agg_kernel(const uint2* __restrict__ hw2,
                                                  const int2* __restrict__ csr,
                                                  const int* __restrict__ offs,
                                                  const float4* __restrict__ bias4,
                                                  float4* __restrict__ xout, int n,
                                                  float* __restrict__ pS,
                                                  float* __restrict__ pQ, int NB) {
    int lane = threadIdx.x & 63;
    int wv = threadIdx.x >> 6;
    int half = lane >> 5;  // 0: even edges, 1: odd edges
    int fl = lane & 31;    // feature group 4*fl..4*fl+3
    float4 bs = bias4[fl];
    float4 s = make_float4(0.f, 0.f, 0.f, 0.f), s2 = make_float4(0.f, 0.f, 0.f, 0.f);
    int nGroups = (n + 3) >> 2;
    for (int grp = blockIdx.x; grp < nGroups; grp += gridDim.x) {
        int node = grp * 4 + wv;
        if (node < n) {
            int p0 = offs[node], p1 = offs[node + 1];
            float4 acc = half ? make_float4(0.f, 0.f, 0.f, 0.f) : bs;
            for (int base = p0; base < p1; base += 64) {
                int cnt = p1 - base;
                if (cnt > 64) cnt = 64;
                int2 e = csr[base + (lane < cnt ? lane : cnt - 1)];
                for (int j = 0; j < cnt; j += 8) {
#pragma unroll
                    for (int u = 0; u < 4; ++u) {
                        int jj = j + 2 * u + half;
                        bool ok = jj < cnt;
                        int sel = ok ? jj : 0;
                        int r = __shfl(e.x, sel, 64);
                        float w = ok ? __int_as_float(__shfl(e.y, sel, 64)) : 0.f;
                        uint2 uu = hw2[(long)r * 32 + fl];
                        acc.x += w * __uint_as_float(uu.x << 16);
                        acc.y += w * __uint_as_float(uu.x & 0xffff0000u);
                        acc.z += w * __uint_as_float(uu.y << 16);
                        acc.w += w * __uint_as_float(uu.y & 0xffff0000u);
                    }
                }
            }
            // combine the two halves (lane and lane^32 hold same features)
            acc.x += __shfl_xor(acc.x, 32, 64);
            acc.y += __shfl_xor(acc.y, 32, 64);
            acc.z += __shfl_xor(acc.z, 32, 64);
            acc.w += __shfl_xor(acc.w, 32, 64);
            float4 x = make_float4(fmaxf(acc.x, 0.f), fmaxf(acc.y, 0.f), fmaxf(acc.z, 0.f),
                                   fmaxf(acc.w, 0.f));
            if (half == 0) {
                xout[(long)node * 32 + fl] = x;
                if (STATS) {
                    s.x += x.x; s.y += x.y; s.z += x.z; s.w += x.w;
                    s2.x += x.x * x.x; s2.y += x.y * x.y;
                    s2.z += x.z * x.z; s2.w += x.w * x.w;
                }
            }
        }
    }
    if (STATS) {
        __shared__ float4 smS[256], smQ[256];
        smS[threadIdx.x] = s;
        smQ[threadIdx.x] = s2;
        __syncthreads();
        if (threadIdx.x < 32) {
            float4 a = smS[threadIdx.x], q = smQ[threadIdx.x];
#pragma unroll
            for (int w2 = 1; w2 < 4; ++w2) {
                float4 b = smS[w2 * 64 + threadIdx.x], c = smQ[w2 * 64 + threadIdx.x];
                a.x += b.x; a.y += b.y; a.z += b.z; a.w += b.w;
                q.x += c.x; q.y += c.y; q.z += c.z; q.w += c.w;
            }
            int f0 = 4 * threadIdx.x;
            pS[(f0 + 0) * NB + blockIdx.x] = a.x;
            pS[(f0 + 1) * NB + blockIdx.x] = a.y;
            pS[(f0 + 2) * NB + blockIdx.x] = a.z;
            pS[(f0 + 3) * NB + blockIdx.x] = a.w;
            pQ[(f0 + 0) * NB + blockIdx.x] = q.x;
            pQ[(f0 + 1) * NB + blockIdx.x] = q.y;
            pQ[(f0 + 2) * NB + blockIdx.x] = q.z;
            pQ[(f0 + 3) * NB + blockIdx.x] = q.w;
        }
    }
}

// ---------------- softmax pooling (bounds in-block, 1024 threads) ----------------

__global__ __launch_bounds__(1024) void pool_kernel(const float* __restrict__ tfidf,
                                                    const int* __restrict__ batch,
                                                    const float* __restrict__ x,
                                                    float* __restrict__ out, int n) {
    int g = blockIdx.x;
    int tid = threadIdx.x;
    __shared__ int sbounds[2];
    if (tid < 2) {
        int target = g + tid;
        int lo = 0, hi = n;
        while (lo < hi) {
            int mid = (lo + hi) >> 1;
            if (batch[mid] < target) lo = mid + 1;
            else hi = mid;
        }
        sbounds[tid] = lo;
    }
    __syncthreads();
    int s0 = sbounds[0], s1 = sbounds[1];
    int d = tid & 127, sub = tid >> 7;  // 8-way node split
    __shared__ float red[1024];
    float m = -1e30f;
    for (int i = s0 + tid; i < s1; i += 1024) m = fmaxf(m, tfidf[i]);
    red[tid] = m;
    __syncthreads();
    for (int off = 512; off > 0; off >>= 1) {
        if (tid < off) red[tid] = fmaxf(red[tid], red[tid + off]);
        __syncthreads();
    }
    m = red[0];
    __syncthreads();
    float s = 0.f;
    for (int i = s0 + tid; i < s1; i += 1024) s += __expf(tfidf[i] - m);
    red[tid] = s;
    __syncthreads();
    for (int off = 512; off > 0; off >>= 1) {
        if (tid < off) red[tid] += red[tid + off];
        __syncthreads();
    }
    s = red[0];
    __syncthreads();
    float acc = 0.f;
    for (int i = s0 + sub; i < s1; i += 8) acc += __expf(tfidf[i] - m) * x[(long)i * D + d];
    red[tid] = acc;
    __syncthreads();
    if (tid < 128) {
        float a = 0.f;
#pragma unroll
        for (int w = 0; w < 8; ++w) a += red[w * 128 + d];
        out[g * D + d] = (s1 > s0) ? a / s : 0.f;
    }
}

// ---------------- launch ----------------

extern "C" void kernel_launch(void* const* d_in, const int* in_sizes, int n_in, void* d_out,
                              int out_size, void* d_ws, size_t ws_size, hipStream_t stream) {
    const int N = in_sizes[0];
    const int E = in_sizes[4];
    const int G = out_size / D;
    const int BN_GRID = 768;
    const int AGG_GRID = 2048;

    const int* x_index = (const int*)d_in[0];
    const float* tfidf = (const float*)d_in[1];
    const int* ei_row = (const int*)d_in[2];
    const int* ei_col = ei_row + E;
    const int* batch = (const int*)d_in[3];
    const float* edge_attr = (const float*)d_in[4];
    const float* emb = (const float*)d_in[5];
    const float* gamma1 = (const float*)d_in[6];
    const float* beta1 = (const float*)d_in[7];
    const float* W1 = (const float*)d_in[8];
    const float* b1 = (const float*)d_in[9];
    const float* gamma2 = (const float*)d_in[10];
    const float* beta2 = (const float*)d_in[11];
    const float* W2 = (const float*)d_in[12];
    const float* b2 = (const float*)d_in[13];
    float* out = (float*)d_out;

    // ---- workspace carve (256B aligned) ----
    size_t off = 0;
    char* base = (char*)d_ws;
    auto carve = [&](size_t bytes) -> void* {
        void* p = base + off;
        off = (off + bytes + 255) & ~(size_t)255;
        return p;
    };
    unsigned short* bufA = (unsigned short*)carve((size_t)N * D * 2);  // h (bf16)
    float* bufB = (float*)carve((size_t)N * D * 4);                    // x (layer output)
    long long* pk = (long long*)carve((size_t)E * 8);                  // packed (e, row)
    int2* csr = (int2*)carve((size_t)E * 8);                           // (row, ea) -> (row, w)
    int* cnt = (int*)carve((size_t)N * 4);                             // zeroed each launch
    float* dis = (float*)carve((size_t)N * 4);
    int* offs = (int*)carve((size_t)(N + 1) * 4);
    int* cursor = (int*)carve((size_t)N * 4);
    int* bsum = (int*)carve(64 * 4);
    float* scale1 = (float*)carve(D * 4);
    float* shift1 = (float*)carve(D * 4);
    float* scale2 = (float*)carve(D * 4);
    float* shift2 = (float*)carve(D * 4);
    float* pS = (float*)carve((size_t)AGG_GRID * D * 4);
    float* pQ = (float*)carve((size_t)AGG_GRID * D * 4);
    (void)ws_size;
    (void)n_in;

    hipMemsetAsync(cnt, 0, (size_t)N * 4, stream);

    // ---- edge preprocessing: CSR (deterministic; shared by both layers) ----
    hist_kernel<<<cdiv(E, 256), 256, 0, stream>>>(ei_col, cnt, E);
    int nb = cdiv(N, 1024);
    scan_chunk_sums<<<nb, 1024, 0, stream>>>(cnt, bsum, N);
    scan_final<<<nb, 1024, 0, stream>>>(cnt, bsum, nb, offs, cursor, N, E);
    scatter_pack<<<cdiv(E, 256), 256, 0, stream>>>(ei_row, ei_col, cursor, pk, E);
    sort_deg_kernel<<<cdiv(N, 4), 256, 0, stream>>>(pk, offs, edge_attr, dis, csr, N);
    fill_w_kernel<<<cdiv(N, 4), 256, 0, stream>>>(offs, dis, csr, N);

    // ---- layer 1 ----
    bn_stats<true><<<BN_GRID, 256, 0, stream>>>(emb, x_index, pS, pQ, N, BN_GRID);
    bn_reduce<<<D, 256, 0, stream>>>(pS, pQ, BN_GRID, gamma1, beta1, scale1, shift1, (float)N);
    gemm_bn<true><<<cdiv(N, 64), 256, 0, stream>>>(emb, x_index, scale1, shift1, W1, bufA, N);
    // agg1 also produces layer-2 BN partials (fused bn_stats)
    agg_kernel<true><<<AGG_GRID, 256, 0, stream>>>((const uint2*)bufA, csr, offs,
                                                   (const float4*)b1, (float4*)bufB, N, pS, pQ,
                                                   AGG_GRID);

    // ---- layer 2 ----
    bn_reduce<<<D, 256, 0, stream>>>(pS, pQ, AGG_GRID, gamma2, beta2, scale2, shift2, (float)N);
    gemm_bn<false><<<cdiv(N, 64), 256, 0, stream>>>(bufB, nullptr, scale2, shift2, W2, bufA, N);
    agg_kernel<false><<<cdiv(N, 4), 256, 0, stream>>>((const uint2*)bufA, csr, offs,
                                                      (const float4*)b2, (float4*)bufB, N,
                                                      nullptr, nullptr, 0);

    // ---- softmax pooling ----
    pool_kernel<<<G, 1024, 0, stream>>>(tfidf, batch, bufB, out, N);
}

// Round 13
// 316.362 us; speedup vs baseline: 2.4842x; 1.1094x over previous
//
#include <hip/hip_runtime.h>
#include <hip/hip_bf16.h>

#define D 128
#define EPSV 1e-5f

static inline int cdiv(int a, int b) { return (a + b - 1) / b; }

typedef __attribute__((ext_vector_type(8))) short short8v;
typedef __attribute__((ext_vector_type(4))) float floatx4;

// bf16 RNE pack
__device__ __forceinline__ unsigned short f2bf(float f) {
    unsigned int x = __float_as_uint(f);
    unsigned int r = x + 0x7fffu + ((x >> 16) & 1u);
    return (unsigned short)(r >> 16);
}

// ---------------- W -> bf16 transposed (once per launch, both layers) ----------------
// WT[n*128 + k] = bf16(W[k*128 + n]); 256 blocks x 128 threads.

__global__ void prep_w(const float* __restrict__ W1, const float* __restrict__ W2,
                       unsigned short* __restrict__ WT1, unsigned short* __restrict__ WT2) {
    int b = blockIdx.x;
    const float* W = (b < D) ? W1 : W2;
    unsigned short* WT = (b < D) ? WT1 : WT2;
    int k = b & (D - 1);
    int n = threadIdx.x;
    WT[n * D + k] = f2bf(W[k * D + n]);
}

// ---------------- edge preprocessing (fully deterministic) ----------------

__global__ void hist_kernel(const int* __restrict__ col, int* __restrict__ cnt, int E_) {
    int e = blockIdx.x * blockDim.x + threadIdx.x;
    if (e >= E_) return;
    atomicAdd(&cnt[col[e]], 1);  // int atomics: result order-independent
}

__global__ void scan_chunk_sums(const int* __restrict__ cnt, int* __restrict__ bsum, int n) {
    __shared__ int sm[1024];
    int i = blockIdx.x * 1024 + threadIdx.x;
    sm[threadIdx.x] = (i < n) ? cnt[i] : 0;
    __syncthreads();
    for (int off = 512; off > 0; off >>= 1) {
        if (threadIdx.x < off) sm[threadIdx.x] += sm[threadIdx.x + off];
        __syncthreads();
    }
    if (threadIdx.x == 0) bsum[blockIdx.x] = sm[0];
}

__global__ void scan_final(const int* __restrict__ cnt, const int* __restrict__ bsum, int nbk,
                           int* __restrict__ offs, int* __restrict__ cursor, int n, int E_) {
    __shared__ int sm[1024];
    __shared__ int sbo;
    int tid = threadIdx.x;
    int bv = (tid < nbk && tid < blockIdx.x) ? bsum[tid] : 0;
    sm[tid] = bv;
    __syncthreads();
    for (int off = 512; off > 0; off >>= 1) {
        if (tid < off) sm[tid] += sm[tid + off];
        __syncthreads();
    }
    if (tid == 0) {
        sbo = sm[0];
        if (blockIdx.x == 0) offs[n] = E_;
    }
    __syncthreads();
    int i = blockIdx.x * 1024 + tid;
    int v = (i < n) ? cnt[i] : 0;
    sm[tid] = v;
    __syncthreads();
    for (int off = 1; off < 1024; off <<= 1) {
        int t = (tid >= off) ? sm[tid - off] : 0;
        __syncthreads();
        sm[tid] += t;
        __syncthreads();
    }
    if (i < n) {
        int excl = sm[tid] - v + sbo;
        offs[i] = excl;
        cursor[i] = excl;
    }
}

// scatter packed (edge_id<<32 | src_row) into CSR slots
__global__ void scatter_pack(const int* __restrict__ row, const int* __restrict__ col,
                             int* __restrict__ cursor, long long* __restrict__ pk, int E_) {
    int e = blockIdx.x * blockDim.x + threadIdx.x;
    if (e >= E_) return;
    int c = col[e];
    int r = row[e];
    int p = atomicAdd(&cursor[c], 1);
    pk[p] = ((long long)e << 32) | (unsigned int)r;
}

// wave-level bitonic sort per node (key = edge id); writes csr=(r, ea),
// deterministic tree-sum for deg -> dis.
__global__ __launch_bounds__(256) void sort_deg_kernel(const long long* __restrict__ pk,
                                                       const int* __restrict__ offs,
                                                       const float* __restrict__ ea,
                                                       float* __restrict__ dis,
                                                       int2* __restrict__ csr, int n) {
    int node = blockIdx.x * 4 + (threadIdx.x >> 6);
    int lane = threadIdx.x & 63;
    if (node >= n) return;
    int p0 = offs[node], p1 = offs[node + 1];
    int deg = p1 - p0;
    if (deg <= 64) {
        long long v = (lane < deg) ? pk[p0 + lane] : 0x7fffffffffffffffLL;
        for (int k = 2; k <= 64; k <<= 1) {
            for (int j = k >> 1; j > 0; j >>= 1) {
                long long partner = __shfl_xor(v, j, 64);
                bool up = ((lane & k) == 0);
                bool keepMin = ((lane & j) == 0);
                long long mn = v < partner ? v : partner;
                long long mx = v < partner ? partner : v;
                v = (up == keepMin) ? mn : mx;
            }
        }
        int e = (int)(v >> 32);
        int r = (int)(v & 0xffffffffLL);
        float av = (lane < deg) ? ea[e] : 0.f;
        if (lane < deg) csr[p0 + lane] = make_int2(r, __float_as_int(av));
        float s = av;
        for (int off = 32; off > 0; off >>= 1) s += __shfl_xor(s, off, 64);
        if (lane == 0) dis[node] = s > 0.f ? rsqrtf(fmaxf(s, EPSV)) : 0.f;
    } else {
        if (lane == 0) {  // deterministic O(d^2) selection fallback (unreachable)
            float dg = 0.f;
            for (int p = p0; p < p1; ++p) {
                long long best = 0x7fffffffffffffffLL;
                for (int q2 = p0; q2 < p1; ++q2) {
                    long long cand = pk[q2];
                    int less = 0;
                    for (int q3 = p0; q3 < p1; ++q3)
                        if (pk[q3] < cand) ++less;
                    if (less == p - p0) { best = cand; break; }
                }
                int e = (int)(best >> 32);
                int r = (int)(best & 0xffffffffLL);
                float av = ea[e];
                csr[p] = make_int2(r, __float_as_int(av));
                dg += av;
            }
            dis[node] = dg > 0.f ? rsqrtf(fmaxf(dg, EPSV)) : 0.f;
        }
    }
}

// finalize weights: (r, ea) -> (r, dis[r]*ea*dis[c])
__global__ __launch_bounds__(256) void fill_w_kernel(const int* __restrict__ offs,
                                                     const float* __restrict__ dis,
                                                     int2* __restrict__ csr, int n) {
    int node = blockIdx.x * 4 + (threadIdx.x >> 6);
    int lane = threadIdx.x & 63;
    if (node >= n) return;
    int p0 = offs[node], p1 = offs[node + 1];
    float dc = dis[node];
    for (int p = p0 + lane; p < p1; p += 64) {
        int2 pr = csr[p];
        float w = dis[pr.x] * __int_as_float(pr.y) * dc;
        csr[p] = make_int2(pr.x, __float_as_int(w));
    }
}

// ---------------- batch norm stats (layer 1: emb gather) ----------------

template <bool GATHER>
__global__ __launch_bounds__(256) void bn_stats(const float* __restrict__ src,
                                                const int* __restrict__ idx,
                                                float* __restrict__ pS,
                                                float* __restrict__ pQ, int n, int NB) {
    int sub = threadIdx.x >> 5;
    int q = threadIdx.x & 31;
    float4 s = make_float4(0, 0, 0, 0), s2 = make_float4(0, 0, 0, 0);
    int stride = gridDim.x * 8;
    int i = blockIdx.x * 8 + sub;
    int r_next = (i < n) ? (GATHER ? idx[i] : i) : 0;
    for (; i < n; i += stride) {
        int r = r_next;
        int i2 = i + stride;
        if (i2 < n) r_next = GATHER ? idx[i2] : i2;
        float4 v = *(const float4*)&src[(long)r * D + q * 4];
        s.x += v.x; s.y += v.y; s.z += v.z; s.w += v.w;
        s2.x += v.x * v.x; s2.y += v.y * v.y; s2.z += v.z * v.z; s2.w += v.w * v.w;
    }
    __shared__ float4 redA[256], redB[256];
    redA[threadIdx.x] = s;
    redB[threadIdx.x] = s2;
    __syncthreads();
    for (int off = 128; off >= 32; off >>= 1) {
        if (threadIdx.x < off) {
            float4 a = redA[threadIdx.x + off], b = redB[threadIdx.x + off];
            redA[threadIdx.x].x += a.x; redA[threadIdx.x].y += a.y;
            redA[threadIdx.x].z += a.z; redA[threadIdx.x].w += a.w;
            redB[threadIdx.x].x += b.x; redB[threadIdx.x].y += b.y;
            redB[threadIdx.x].z += b.z; redB[threadIdx.x].w += b.w;
        }
        __syncthreads();
    }
    if (threadIdx.x < 32) {
        float4 a = redA[threadIdx.x], b = redB[threadIdx.x];
        int bofs = blockIdx.x;
        pS[(q * 4 + 0) * NB + bofs] = a.x;
        pS[(q * 4 + 1) * NB + bofs] = a.y;
        pS[(q * 4 + 2) * NB + bofs] = a.z;
        pS[(q * 4 + 3) * NB + bofs] = a.w;
        pQ[(q * 4 + 0) * NB + bofs] = b.x;
        pQ[(q * 4 + 1) * NB + bofs] = b.y;
        pQ[(q * 4 + 2) * NB + bofs] = b.z;
        pQ[(q * 4 + 3) * NB + bofs] = b.w;
    }
}

__global__ __launch_bounds__(256) void bn_reduce(const float* __restrict__ pS,
                                                 const float* __restrict__ pQ, int nb,
                                                 const float* __restrict__ gamma,
                                                 const float* __restrict__ beta,
                                                 float* __restrict__ scale,
                                                 float* __restrict__ shift, float n) {
    int d = blockIdx.x;
    int tid = threadIdx.x;
    float s = 0.f, q = 0.f;
    for (int b = tid; b < nb; b += 256) {
        s += pS[d * nb + b];
        q += pQ[d * nb + b];
    }
    __shared__ float smS[256], smQ[256];
    smS[tid] = s;
    smQ[tid] = q;
    __syncthreads();
    for (int off = 128; off > 0; off >>= 1) {
        if (tid < off) {
            smS[tid] += smS[tid + off];
            smQ[tid] += smQ[tid + off];
        }
        __syncthreads();
    }
    if (tid == 0) {
        float mean = smS[0] / n;
        float var = smQ[0] / n - mean * mean;
        float rstd = rsqrtf(var + EPSV);
        float sc = gamma[d] * rstd;
        scale[d] = sc;
        shift[d] = beta[d] - mean * sc;
    }
}

// ---------------- MFMA GEMM: h = bf16(src*scale+shift) @ bf16(W), out bf16 ----------
// 64 rows/block, 4 waves: wave wv owns rows wv*16..wv*16+15. 16x16x32 bf16 MFMA,
// 8 col-tiles x 4 k-steps per wave. A staged [r][k] bf16 stride 136 shorts,
// B = W^T staged [n][k] bf16 stride 136; 16B chunks XOR-swizzled by (row&15)
// to spread banks. Epilogue: acc -> LDS floats (reuse wsb) -> coalesced stores.

template <bool GATHER>
__global__ __launch_bounds__(256) void gemm_mfma(const float* __restrict__ src,
                                                 const int* __restrict__ idx,
                                                 const float* __restrict__ scale,
                                                 const float* __restrict__ shift,
                                                 const unsigned short* __restrict__ WTb,
                                                 unsigned short* __restrict__ outb, int n) {
    __shared__ unsigned short xsb[64 * 136];   // 17.0 KB
    __shared__ unsigned short wsb[128 * 136];  // 34.0 KB (reused as float scratch in epi)
    int tid = threadIdx.x;
    int r0 = blockIdx.x * 64;
    const float4* scale4 = (const float4*)scale;
    const float4* shift4 = (const float4*)shift;
    // stage A: 64 rows x 16 chunks (8 bf16 each)
    for (int it = 0; it < 4; ++it) {
        int flat = it * 256 + tid;  // 0..1023
        int r = flat >> 4;
        int c16 = flat & 15;
        int gr = r0 + r;
        float4 v0 = make_float4(0, 0, 0, 0), v1 = make_float4(0, 0, 0, 0);
        if (gr < n) {
            int srow = GATHER ? idx[gr] : gr;
            float4 x0 = *(const float4*)&src[(long)srow * D + c16 * 8];
            float4 x1 = *(const float4*)&src[(long)srow * D + c16 * 8 + 4];
            float4 sa = scale4[c16 * 2], sb = shift4[c16 * 2];
            float4 sc = scale4[c16 * 2 + 1], sd = shift4[c16 * 2 + 1];
            v0 = make_float4(x0.x * sa.x + sb.x, x0.y * sa.y + sb.y, x0.z * sa.z + sb.z,
                             x0.w * sa.w + sb.w);
            v1 = make_float4(x1.x * sc.x + sd.x, x1.y * sc.y + sd.y, x1.z * sc.z + sd.z,
                             x1.w * sc.w + sd.w);
        }
        int phys = c16 ^ (r & 15);
        ushort4 o0 = make_ushort4(f2bf(v0.x), f2bf(v0.y), f2bf(v0.z), f2bf(v0.w));
        ushort4 o1 = make_ushort4(f2bf(v1.x), f2bf(v1.y), f2bf(v1.z), f2bf(v1.w));
        *(ushort4*)&xsb[r * 136 + phys * 8] = o0;
        *(ushort4*)&xsb[r * 136 + phys * 8 + 4] = o1;
    }
    // stage B: 128 rows (n) x 16 chunks
    for (int it = 0; it < 8; ++it) {
        int flat = it * 256 + tid;  // 0..2047
        int nrow = flat >> 4;
        int c16 = flat & 15;
        int phys = c16 ^ (nrow & 15);
        uint4 w = *(const uint4*)&WTb[nrow * D + c16 * 8];
        *(uint4*)&wsb[nrow * 136 + phys * 8] = w;
    }
    __syncthreads();
    int wv = tid >> 6;
    int lane = tid & 63;
    int m = lane & 15, q = lane >> 4;
    int r0w = wv * 16;
    floatx4 acc[8];
#pragma unroll
    for (int t = 0; t < 8; ++t) acc[t] = (floatx4)(0.f);
#pragma unroll
    for (int ks = 0; ks < 4; ++ks) {
        int c16 = ks * 4 + q;
        short8v a = *(short8v*)&xsb[(r0w + m) * 136 + (c16 ^ ((r0w + m) & 15)) * 8];
#pragma unroll
        for (int t = 0; t < 8; ++t) {
            short8v b = *(short8v*)&wsb[(t * 16 + m) * 136 + (c16 ^ m) * 8];
            acc[t] = __builtin_amdgcn_mfma_f32_16x16x32_bf16(a, b, acc[t], 0, 0, 0);
        }
    }
    __syncthreads();
    float* fl = (float*)wsb;  // 64 x 132 floats = 33.8 KB <= 34.0 KB
#pragma unroll
    for (int t = 0; t < 8; ++t) {
#pragma unroll
        for (int r = 0; r < 4; ++r) {
            fl[(r0w + q * 4 + r) * 132 + t * 16 + m] = acc[t][r];
        }
    }
    __syncthreads();
    for (int it = 0; it < 4; ++it) {
        int c = it * 256 + tid;  // 1024 chunks
        int r = c >> 4;
        int k8 = (c & 15) * 8;
        int gr = r0 + r;
        if (gr < n) {
            float4 v0 = *(float4*)&fl[r * 132 + k8];
            float4 v1 = *(float4*)&fl[r * 132 + k8 + 4];
            ushort4 o0 = make_ushort4(f2bf(v0.x), f2bf(v0.y), f2bf(v0.z), f2bf(v0.w));
            ushort4 o1 = make_ushort4(f2bf(v1.x), f2bf(v1.y), f2bf(v1.z), f2bf(v1.w));
            *(ushort4*)&outb[(long)gr * D + k8] = o0;
            *(ushort4*)&outb[(long)gr * D + k8 + 4] = o1;
        }
    }
}

// ---------------- aggregation: dual-edge gathers ----------------
// bf16 h rows (256B). Wave = two 32-lane halves, each half gathers one row
// (uint2/lane); one gather instruction covers two edges. (r,w) via __shfl
// from the wave's coalesced csr chunk. STATS variant accumulates next
// layer's BN partials.

template <bool STATS>
__global__ __launch_bounds__(256) void agg_kernel(const uint2* __restrict__ hw2,
                                                  const int2* __restrict__ csr,
                                                  const int* __restrict__ offs,
                                                  const float4* __restrict__ bias4,
                                                  float4* __restrict__ xout, int n,
                                                  float* __restrict__ pS,
                                                  float* __restrict__ pQ, int NB) {
    int lane = threadIdx.x & 63;
    int wv = threadIdx.x >> 6;
    int half = lane >> 5;  // 0: even edges, 1: odd edges
    int fl = lane & 31;    // feature group 4*fl..4*fl+3
    float4 bs = bias4[fl];
    float4 s = make_float4(0.f, 0.f, 0.f, 0.f), s2 = make_float4(0.f, 0.f, 0.f, 0.f);
    int nGroups = (n + 3) >> 2;
    for (int grp = blockIdx.x; grp < nGroups; grp += gridDim.x) {
        int node = grp * 4 + wv;
        if (node < n) {
            int p0 = offs[node], p1 = offs[node + 1];
            float4 acc = half ? make_float4(0.f, 0.f, 0.f, 0.f) : bs;
            for (int base = p0; base < p1; base += 64) {
                int cnt = p1 - base;
                if (cnt > 64) cnt = 64;
                int2 e = csr[base + (lane < cnt ? lane : cnt - 1)];
                for (int j = 0; j < cnt; j += 8) {
#pragma unroll
                    for (int u = 0; u < 4; ++u) {
                        int jj = j + 2 * u + half;
                        bool ok = jj < cnt;
                        int sel = ok ? jj : 0;
                        int r = __shfl(e.x, sel, 64);
                        float w = ok ? __int_as_float(__shfl(e.y, sel, 64)) : 0.f;
                        uint2 uu = hw2[(long)r * 32 + fl];
                        acc.x += w * __uint_as_float(uu.x << 16);
                        acc.y += w * __uint_as_float(uu.x & 0xffff0000u);
                        acc.z += w * __uint_as_float(uu.y << 16);
                        acc.w += w * __uint_as_float(uu.y & 0xffff0000u);
                    }
                }
            }
            acc.x += __shfl_xor(acc.x, 32, 64);
            acc.y += __shfl_xor(acc.y, 32, 64);
            acc.z += __shfl_xor(acc.z, 32, 64);
            acc.w += __shfl_xor(acc.w, 32, 64);
            float4 x = make_float4(fmaxf(acc.x, 0.f), fmaxf(acc.y, 0.f), fmaxf(acc.z, 0.f),
                                   fmaxf(acc.w, 0.f));
            if (half == 0) {
                xout[(long)node * 32 + fl] = x;
                if (STATS) {
                    s.x += x.x; s.y += x.y; s.z += x.z; s.w += x.w;
                    s2.x += x.x * x.x; s2.y += x.y * x.y;
                    s2.z += x.z * x.z; s2.w += x.w * x.w;
                }
            }
        }
    }
    if (STATS) {
        __shared__ float4 smS[256], smQ[256];
        smS[threadIdx.x] = s;
        smQ[threadIdx.x] = s2;
        __syncthreads();
        if (threadIdx.x < 32) {
            float4 a = smS[threadIdx.x], q = smQ[threadIdx.x];
#pragma unroll
            for (int w2 = 1; w2 < 4; ++w2) {
                float4 b = smS[w2 * 64 + threadIdx.x], c = smQ[w2 * 64 + threadIdx.x];
                a.x += b.x; a.y += b.y; a.z += b.z; a.w += b.w;
                q.x += c.x; q.y += c.y; q.z += c.z; q.w += c.w;
            }
            int f0 = 4 * threadIdx.x;
            pS[(f0 + 0) * NB + blockIdx.x] = a.x;
            pS[(f0 + 1) * NB + blockIdx.x] = a.y;
            pS[(f0 + 2) * NB + blockIdx.x] = a.z;
            pS[(f0 + 3) * NB + blockIdx.x] = a.w;
            pQ[(f0 + 0) * NB + blockIdx.x] = q.x;
            pQ[(f0 + 1) * NB + blockIdx.x] = q.y;
            pQ[(f0 + 2) * NB + blockIdx.x] = q.z;
            pQ[(f0 + 3) * NB + blockIdx.x] = q.w;
        }
    }
}

// ---------------- softmax pooling (bounds in-block, 1024 threads) ----------------

__global__ __launch_bounds__(1024) void pool_kernel(const float* __restrict__ tfidf,
                                                    const int* __restrict__ batch,
                                                    const float* __restrict__ x,
                                                    float* __restrict__ out, int n) {
    int g = blockIdx.x;
    int tid = threadIdx.x;
    __shared__ int sbounds[2];
    if (tid < 2) {
        int target = g + tid;
        int lo = 0, hi = n;
        while (lo < hi) {
            int mid = (lo + hi) >> 1;
            if (batch[mid] < target) lo = mid + 1;
            else hi = mid;
        }
        sbounds[tid] = lo;
    }
    __syncthreads();
    int s0 = sbounds[0], s1 = sbounds[1];
    int d = tid & 127, sub = tid >> 7;  // 8-way node split
    __shared__ float red[1024];
    float m = -1e30f;
    for (int i = s0 + tid; i < s1; i += 1024) m = fmaxf(m, tfidf[i]);
    red[tid] = m;
    __syncthreads();
    for (int off = 512; off > 0; off >>= 1) {
        if (tid < off) red[tid] = fmaxf(red[tid], red[tid + off]);
        __syncthreads();
    }
    m = red[0];
    __syncthreads();
    float s = 0.f;
    for (int i = s0 + tid; i < s1; i += 1024) s += __expf(tfidf[i] - m);
    red[tid] = s;
    __syncthreads();
    for (int off = 512; off > 0; off >>= 1) {
        if (tid < off) red[tid] += red[tid + off];
        __syncthreads();
    }
    s = red[0];
    __syncthreads();
    float acc = 0.f;
    for (int i = s0 + sub; i < s1; i += 8) acc += __expf(tfidf[i] - m) * x[(long)i * D + d];
    red[tid] = acc;
    __syncthreads();
    if (tid < 128) {
        float a = 0.f;
#pragma unroll
        for (int w = 0; w < 8; ++w) a += red[w * 128 + d];
        out[g * D + d] = (s1 > s0) ? a / s : 0.f;
    }
}

// ---------------- launch ----------------

extern "C" void kernel_launch(void* const* d_in, const int* in_sizes, int n_in, void* d_out,
                              int out_size, void* d_ws, size_t ws_size, hipStream_t stream) {
    const int N = in_sizes[0];
    const int E = in_sizes[4];
    const int G = out_size / D;
    const int BN_GRID = 768;
    const int AGG_GRID = 2048;

    const int* x_index = (const int*)d_in[0];
    const float* tfidf = (const float*)d_in[1];
    const int* ei_row = (const int*)d_in[2];
    const int* ei_col = ei_row + E;
    const int* batch = (const int*)d_in[3];
    const float* edge_attr = (const float*)d_in[4];
    const float* emb = (const float*)d_in[5];
    const float* gamma1 = (const float*)d_in[6];
    const float* beta1 = (const float*)d_in[7];
    const float* W1 = (const float*)d_in[8];
    const float* b1 = (const float*)d_in[9];
    const float* gamma2 = (const float*)d_in[10];
    const float* beta2 = (const float*)d_in[11];
    const float* W2 = (const float*)d_in[12];
    const float* b2 = (const float*)d_in[13];
    float* out = (float*)d_out;

    // ---- workspace carve (256B aligned) ----
    size_t off = 0;
    char* base = (char*)d_ws;
    auto carve = [&](size_t bytes) -> void* {
        void* p = base + off;
        off = (off + bytes + 255) & ~(size_t)255;
        return p;
    };
    unsigned short* bufA = (unsigned short*)carve((size_t)N * D * 2);  // h (bf16)
    float* bufB = (float*)carve((size_t)N * D * 4);                    // x (layer output)
    long long* pk = (long long*)carve((size_t)E * 8);                  // packed (e, row)
    int2* csr = (int2*)carve((size_t)E * 8);                           // (row, ea) -> (row, w)
    int* cnt = (int*)carve((size_t)N * 4);                             // zeroed each launch
    float* dis = (float*)carve((size_t)N * 4);
    int* offs = (int*)carve((size_t)(N + 1) * 4);
    int* cursor = (int*)carve((size_t)N * 4);
    int* bsum = (int*)carve(64 * 4);
    float* scale1 = (float*)carve(D * 4);
    float* shift1 = (float*)carve(D * 4);
    float* scale2 = (float*)carve(D * 4);
    float* shift2 = (float*)carve(D * 4);
    unsigned short* WT1b = (unsigned short*)carve((size_t)D * D * 2);
    unsigned short* WT2b = (unsigned short*)carve((size_t)D * D * 2);
    float* pS = (float*)carve((size_t)AGG_GRID * D * 4);
    float* pQ = (float*)carve((size_t)AGG_GRID * D * 4);
    (void)ws_size;
    (void)n_in;

    hipMemsetAsync(cnt, 0, (size_t)N * 4, stream);

    // ---- W -> bf16 transposed (both layers; no deps) ----
    prep_w<<<2 * D, D, 0, stream>>>(W1, W2, WT1b, WT2b);

    // ---- edge preprocessing: CSR (deterministic; shared by both layers) ----
    hist_kernel<<<cdiv(E, 256), 256, 0, stream>>>(ei_col, cnt, E);
    int nb = cdiv(N, 1024);
    scan_chunk_sums<<<nb, 1024, 0, stream>>>(cnt, bsum, N);
    scan_final<<<nb, 1024, 0, stream>>>(cnt, bsum, nb, offs, cursor, N, E);
    scatter_pack<<<cdiv(E, 256), 256, 0, stream>>>(ei_row, ei_col, cursor, pk, E);
    sort_deg_kernel<<<cdiv(N, 4), 256, 0, stream>>>(pk, offs, edge_attr, dis, csr, N);
    fill_w_kernel<<<cdiv(N, 4), 256, 0, stream>>>(offs, dis, csr, N);

    // ---- layer 1 ----
    bn_stats<true><<<BN_GRID, 256, 0, stream>>>(emb, x_index, pS, pQ, N, BN_GRID);
    bn_reduce<<<D, 256, 0, stream>>>(pS, pQ, BN_GRID, gamma1, beta1, scale1, shift1, (float)N);
    gemm_mfma<true><<<cdiv(N, 64), 256, 0, stream>>>(emb, x_index, scale1, shift1, WT1b, bufA,
                                                     N);
    // agg1 also produces layer-2 BN partials (fused bn_stats)
    agg_kernel<true><<<AGG_GRID, 256, 0, stream>>>((const uint2*)bufA, csr, offs,
                                                   (const float4*)b1, (float4*)bufB, N, pS, pQ,
                                                   AGG_GRID);

    // ---- layer 2 ----
    bn_reduce<<<D, 256, 0, stream>>>(pS, pQ, AGG_GRID, gamma2, beta2, scale2, shift2, (float)N);
    gemm_mfma<false><<<cdiv(N, 64), 256, 0, stream>>>(bufB, nullptr, scale2, shift2, WT2b,
                                                      bufA, N);
    agg_kernel<false><<<cdiv(N, 4), 256, 0, stream>>>((const uint2*)bufA, csr, offs,
                                                      (const float4*)b2, (float4*)bufB, N,
                                                      nullptr, nullptr, 0);

    // ---- softmax pooling ----
    pool_kernel<<<G, 1024, 0, stream>>>(tfidf, batch, bufB, out, N);
}

// Round 14
// 297.086 us; speedup vs baseline: 2.6454x; 1.0649x over previous
//
#include <hip/hip_runtime.h>
#include <hip/hip_bf16.h>

#define D 128
#define EPSV 1e-5f

static inline int cdiv(int a, int b) { return (a + b - 1) / b; }

typedef __attribute__((ext_vector_type(8))) short short8v;
typedef __attribute__((ext_vector_type(4))) float floatx4;

// bf16 RNE pack
__device__ __forceinline__ unsigned short f2bf(float f) {
    unsigned int x = __float_as_uint(f);
    unsigned int r = x + 0x7fffu + ((x >> 16) & 1u);
    return (unsigned short)(r >> 16);
}

// ---------------- W -> bf16 transposed (once per launch, both layers) ----------------

__global__ void prep_w(const float* __restrict__ W1, const float* __restrict__ W2,
                       unsigned short* __restrict__ WT1, unsigned short* __restrict__ WT2) {
    int b = blockIdx.x;
    const float* W = (b < D) ? W1 : W2;
    unsigned short* WT = (b < D) ? WT1 : WT2;
    int k = b & (D - 1);
    int n = threadIdx.x;
    WT[n * D + k] = f2bf(W[k * D + n]);
}

// ---------------- edge preprocessing (fully deterministic) ----------------
// hist also captures arrival rank (placement canonicalized later by sort).

__global__ void hist_rank_kernel(const int* __restrict__ col, int* __restrict__ cnt,
                                 int* __restrict__ rank, int E_) {
    int e = blockIdx.x * blockDim.x + threadIdx.x;
    if (e >= E_) return;
    rank[e] = atomicAdd(&cnt[col[e]], 1);
}

__global__ void scan_chunk_sums(const int* __restrict__ cnt, int* __restrict__ bsum, int n) {
    __shared__ int sm[1024];
    int i = blockIdx.x * 1024 + threadIdx.x;
    sm[threadIdx.x] = (i < n) ? cnt[i] : 0;
    __syncthreads();
    for (int off = 512; off > 0; off >>= 1) {
        if (threadIdx.x < off) sm[threadIdx.x] += sm[threadIdx.x + off];
        __syncthreads();
    }
    if (threadIdx.x == 0) bsum[blockIdx.x] = sm[0];
}

__global__ void scan_final(const int* __restrict__ cnt, const int* __restrict__ bsum, int nbk,
                           int* __restrict__ offs, int n, int E_) {
    __shared__ int sm[1024];
    __shared__ int sbo;
    int tid = threadIdx.x;
    int bv = (tid < nbk && tid < blockIdx.x) ? bsum[tid] : 0;
    sm[tid] = bv;
    __syncthreads();
    for (int off = 512; off > 0; off >>= 1) {
        if (tid < off) sm[tid] += sm[tid + off];
        __syncthreads();
    }
    if (tid == 0) {
        sbo = sm[0];
        if (blockIdx.x == 0) offs[n] = E_;
    }
    __syncthreads();
    int i = blockIdx.x * 1024 + tid;
    int v = (i < n) ? cnt[i] : 0;
    sm[tid] = v;
    __syncthreads();
    for (int off = 1; off < 1024; off <<= 1) {
        int t = (tid >= off) ? sm[tid - off] : 0;
        __syncthreads();
        sm[tid] += t;
        __syncthreads();
    }
    if (i < n) offs[i] = sm[tid] - v + sbo;
}

// scatter packed (src_row<<32 | ea_bits) into CSR slot offs[col]+rank.
// No atomics; only random access is offs[col] (200 KB, L2-resident).
__global__ void scatter_pack(const int* __restrict__ row, const int* __restrict__ col,
                             const float* __restrict__ ea, const int* __restrict__ rank,
                             const int* __restrict__ offs, long long* __restrict__ pk,
                             int E_) {
    int e = blockIdx.x * blockDim.x + threadIdx.x;
    if (e >= E_) return;
    int p = offs[col[e]] + rank[e];
    pk[p] = ((long long)row[e] << 32) | (unsigned int)__float_as_int(ea[e]);
}

// wave-level bitonic sort per node; key = (row, ea_bits) -- equal keys are
// identical entries so the sorted array is deterministic. Unpacks csr=(r,ea)
// directly (zero gathers); deterministic tree-sum of ea -> dis.
__global__ __launch_bounds__(256) void sort_deg_kernel(const long long* __restrict__ pk,
                                                       const int* __restrict__ offs,
                                                       float* __restrict__ dis,
                                                       int2* __restrict__ csr, int n) {
    int node = blockIdx.x * 4 + (threadIdx.x >> 6);
    int lane = threadIdx.x & 63;
    if (node >= n) return;
    int p0 = offs[node], p1 = offs[node + 1];
    int deg = p1 - p0;
    if (deg <= 64) {
        long long v = (lane < deg) ? pk[p0 + lane] : 0x7fffffffffffffffLL;
        for (int k = 2; k <= 64; k <<= 1) {
            for (int j = k >> 1; j > 0; j >>= 1) {
                long long partner = __shfl_xor(v, j, 64);
                bool up = ((lane & k) == 0);
                bool keepMin = ((lane & j) == 0);
                long long mn = v < partner ? v : partner;
                long long mx = v < partner ? partner : v;
                v = (up == keepMin) ? mn : mx;
            }
        }
        int r = (int)(v >> 32);
        int eab = (int)(v & 0xffffffffLL);
        if (lane < deg) csr[p0 + lane] = make_int2(r, eab);
        float av = (lane < deg) ? __int_as_float(eab) : 0.f;
        float s = av;
        for (int off = 32; off > 0; off >>= 1) s += __shfl_xor(s, off, 64);
        if (lane == 0) dis[node] = s > 0.f ? rsqrtf(fmaxf(s, EPSV)) : 0.f;
    } else {
        if (lane == 0) {  // deterministic O(d^2) selection fallback (unreachable)
            float dg = 0.f;
            for (int p = p0; p < p1; ++p) {
                long long best = 0x7fffffffffffffffLL;
                for (int q2 = p0; q2 < p1; ++q2) {
                    long long cand = pk[q2];
                    int less = 0;
                    for (int q3 = p0; q3 < p1; ++q3)
                        if (pk[q3] < cand) ++less;
                    if (less == p - p0) { best = cand; break; }
                }
                int r = (int)(best >> 32);
                int eab = (int)(best & 0xffffffffLL);
                csr[p] = make_int2(r, eab);
                dg += __int_as_float(eab);
            }
            dis[node] = dg > 0.f ? rsqrtf(fmaxf(dg, EPSV)) : 0.f;
        }
    }
}

// finalize weights: (r, ea) -> (r, dis[r]*ea*dis[c])
__global__ __launch_bounds__(256) void fill_w_kernel(const int* __restrict__ offs,
                                                     const float* __restrict__ dis,
                                                     int2* __restrict__ csr, int n) {
    int node = blockIdx.x * 4 + (threadIdx.x >> 6);
    int lane = threadIdx.x & 63;
    if (node >= n) return;
    int p0 = offs[node], p1 = offs[node + 1];
    float dc = dis[node];
    for (int p = p0 + lane; p < p1; p += 64) {
        int2 pr = csr[p];
        float w = dis[pr.x] * __int_as_float(pr.y) * dc;
        csr[p] = make_int2(pr.x, __float_as_int(w));
    }
}

// ---------------- batch norm stats (layer 1: emb gather) ----------------

template <bool GATHER>
__global__ __launch_bounds__(256) void bn_stats(const float* __restrict__ src,
                                                const int* __restrict__ idx,
                                                float* __restrict__ pS,
                                                float* __restrict__ pQ, int n, int NB) {
    int sub = threadIdx.x >> 5;
    int q = threadIdx.x & 31;
    float4 s = make_float4(0, 0, 0, 0), s2 = make_float4(0, 0, 0, 0);
    int stride = gridDim.x * 8;
    int i = blockIdx.x * 8 + sub;
    int r_next = (i < n) ? (GATHER ? idx[i] : i) : 0;
    for (; i < n; i += stride) {
        int r = r_next;
        int i2 = i + stride;
        if (i2 < n) r_next = GATHER ? idx[i2] : i2;
        float4 v = *(const float4*)&src[(long)r * D + q * 4];
        s.x += v.x; s.y += v.y; s.z += v.z; s.w += v.w;
        s2.x += v.x * v.x; s2.y += v.y * v.y; s2.z += v.z * v.z; s2.w += v.w * v.w;
    }
    __shared__ float4 redA[256], redB[256];
    redA[threadIdx.x] = s;
    redB[threadIdx.x] = s2;
    __syncthreads();
    for (int off = 128; off >= 32; off >>= 1) {
        if (threadIdx.x < off) {
            float4 a = redA[threadIdx.x + off], b = redB[threadIdx.x + off];
            redA[threadIdx.x].x += a.x; redA[threadIdx.x].y += a.y;
            redA[threadIdx.x].z += a.z; redA[threadIdx.x].w += a.w;
            redB[threadIdx.x].x += b.x; redB[threadIdx.x].y += b.y;
            redB[threadIdx.x].z += b.z; redB[threadIdx.x].w += b.w;
        }
        __syncthreads();
    }
    if (threadIdx.x < 32) {
        float4 a = redA[threadIdx.x], b = redB[threadIdx.x];
        int bofs = blockIdx.x;
        pS[(q * 4 + 0) * NB + bofs] = a.x;
        pS[(q * 4 + 1) * NB + bofs] = a.y;
        pS[(q * 4 + 2) * NB + bofs] = a.z;
        pS[(q * 4 + 3) * NB + bofs] = a.w;
        pQ[(q * 4 + 0) * NB + bofs] = b.x;
        pQ[(q * 4 + 1) * NB + bofs] = b.y;
        pQ[(q * 4 + 2) * NB + bofs] = b.z;
        pQ[(q * 4 + 3) * NB + bofs] = b.w;
    }
}

__global__ __launch_bounds__(256) void bn_reduce(const float* __restrict__ pS,
                                                 const float* __restrict__ pQ, int nb,
                                                 const float* __restrict__ gamma,
                                                 const float* __restrict__ beta,
                                                 float* __restrict__ scale,
                                                 float* __restrict__ shift, float n) {
    int d = blockIdx.x;
    int tid = threadIdx.x;
    float s = 0.f, q = 0.f;
    for (int b = tid; b < nb; b += 256) {
        s += pS[d * nb + b];
        q += pQ[d * nb + b];
    }
    __shared__ float smS[256], smQ[256];
    smS[tid] = s;
    smQ[tid] = q;
    __syncthreads();
    for (int off = 128; off > 0; off >>= 1) {
        if (tid < off) {
            smS[tid] += smS[tid + off];
            smQ[tid] += smQ[tid + off];
        }
        __syncthreads();
    }
    if (tid == 0) {
        float mean = smS[0] / n;
        float var = smQ[0] / n - mean * mean;
        float rstd = rsqrtf(var + EPSV);
        float sc = gamma[d] * rstd;
        scale[d] = sc;
        shift[d] = beta[d] - mean * sc;
    }
}

// ---------------- MFMA GEMM: h = bf16(src*scale+shift) @ bf16(W), out bf16 ----------

template <bool GATHER>
__global__ __launch_bounds__(256) void gemm_mfma(const float* __restrict__ src,
                                                 const int* __restrict__ idx,
                                                 const float* __restrict__ scale,
                                                 const float* __restrict__ shift,
                                                 const unsigned short* __restrict__ WTb,
                                                 unsigned short* __restrict__ outb, int n) {
    __shared__ unsigned short xsb[64 * 136];   // 17.0 KB
    __shared__ unsigned short wsb[128 * 136];  // 34.0 KB (reused as float scratch in epi)
    int tid = threadIdx.x;
    int r0 = blockIdx.x * 64;
    const float4* scale4 = (const float4*)scale;
    const float4* shift4 = (const float4*)shift;
    for (int it = 0; it < 4; ++it) {
        int flat = it * 256 + tid;  // 0..1023
        int r = flat >> 4;
        int c16 = flat & 15;
        int gr = r0 + r;
        float4 v0 = make_float4(0, 0, 0, 0), v1 = make_float4(0, 0, 0, 0);
        if (gr < n) {
            int srow = GATHER ? idx[gr] : gr;
            float4 x0 = *(const float4*)&src[(long)srow * D + c16 * 8];
            float4 x1 = *(const float4*)&src[(long)srow * D + c16 * 8 + 4];
            float4 sa = scale4[c16 * 2], sb = shift4[c16 * 2];
            float4 sc = scale4[c16 * 2 + 1], sd = shift4[c16 * 2 + 1];
            v0 = make_float4(x0.x * sa.x + sb.x, x0.y * sa.y + sb.y, x0.z * sa.z + sb.z,
                             x0.w * sa.w + sb.w);
            v1 = make_float4(x1.x * sc.x + sd.x, x1.y * sc.y + sd.y, x1.z * sc.z + sd.z,
                             x1.w * sc.w + sd.w);
        }
        int phys = c16 ^ (r & 15);
        ushort4 o0 = make_ushort4(f2bf(v0.x), f2bf(v0.y), f2bf(v0.z), f2bf(v0.w));
        ushort4 o1 = make_ushort4(f2bf(v1.x), f2bf(v1.y), f2bf(v1.z), f2bf(v1.w));
        *(ushort4*)&xsb[r * 136 + phys * 8] = o0;
        *(ushort4*)&xsb[r * 136 + phys * 8 + 4] = o1;
    }
    for (int it = 0; it < 8; ++it) {
        int flat = it * 256 + tid;  // 0..2047
        int nrow = flat >> 4;
        int c16 = flat & 15;
        int phys = c16 ^ (nrow & 15);
        uint4 w = *(const uint4*)&WTb[nrow * D + c16 * 8];
        *(uint4*)&wsb[nrow * 136 + phys * 8] = w;
    }
    __syncthreads();
    int wv = tid >> 6;
    int lane = tid & 63;
    int m = lane & 15, q = lane >> 4;
    int r0w = wv * 16;
    floatx4 acc[8];
#pragma unroll
    for (int t = 0; t < 8; ++t) acc[t] = (floatx4)(0.f);
#pragma unroll
    for (int ks = 0; ks < 4; ++ks) {
        int c16 = ks * 4 + q;
        short8v a = *(short8v*)&xsb[(r0w + m) * 136 + (c16 ^ ((r0w + m) & 15)) * 8];
#pragma unroll
        for (int t = 0; t < 8; ++t) {
            short8v b = *(short8v*)&wsb[(t * 16 + m) * 136 + (c16 ^ m) * 8];
            acc[t] = __builtin_amdgcn_mfma_f32_16x16x32_bf16(a, b, acc[t], 0, 0, 0);
        }
    }
    __syncthreads();
    float* fl = (float*)wsb;  // 64 x 132 floats
#pragma unroll
    for (int t = 0; t < 8; ++t) {
#pragma unroll
        for (int r = 0; r < 4; ++r) {
            fl[(r0w + q * 4 + r) * 132 + t * 16 + m] = acc[t][r];
        }
    }
    __syncthreads();
    for (int it = 0; it < 4; ++it) {
        int c = it * 256 + tid;
        int r = c >> 4;
        int k8 = (c & 15) * 8;
        int gr = r0 + r;
        if (gr < n) {
            float4 v0 = *(float4*)&fl[r * 132 + k8];
            float4 v1 = *(float4*)&fl[r * 132 + k8 + 4];
            ushort4 o0 = make_ushort4(f2bf(v0.x), f2bf(v0.y), f2bf(v0.z), f2bf(v0.w));
            ushort4 o1 = make_ushort4(f2bf(v1.x), f2bf(v1.y), f2bf(v1.z), f2bf(v1.w));
            *(ushort4*)&outb[(long)gr * D + k8] = o0;
            *(ushort4*)&outb[(long)gr * D + k8 + 4] = o1;
        }
    }
}

// ---------------- aggregation: dual-edge gathers ----------------

template <bool STATS>
__global__ __launch_bounds__(256) void agg_kernel(const uint2* __restrict__ hw2,
                                                  const int2* __restrict__ csr,
                                                  const int* __restrict__ offs,
                                                  const float4* __restrict__ bias4,
                                                  float4* __restrict__ xout, int n,
                                                  float* __restrict__ pS,
                                                  float* __restrict__ pQ, int NB) {
    int lane = threadIdx.x & 63;
    int wv = threadIdx.x >> 6;
    int half = lane >> 5;
    int fl = lane & 31;
    float4 bs = bias4[fl];
    float4 s = make_float4(0.f, 0.f, 0.f, 0.f), s2 = make_float4(0.f, 0.f, 0.f, 0.f);
    int nGroups = (n + 3) >> 2;
    for (int grp = blockIdx.x; grp < nGroups; grp += gridDim.x) {
        int node = grp * 4 + wv;
        if (node < n) {
            int p0 = offs[node], p1 = offs[node + 1];
            float4 acc = half ? make_float4(0.f, 0.f, 0.f, 0.f) : bs;
            for (int base = p0; base < p1; base += 64) {
                int cnt = p1 - base;
                if (cnt > 64) cnt = 64;
                int2 e = csr[base + (lane < cnt ? lane : cnt - 1)];
                for (int j = 0; j < cnt; j += 8) {
#pragma unroll
                    for (int u = 0; u < 4; ++u) {
                        int jj = j + 2 * u + half;
                        bool ok = jj < cnt;
                        int sel = ok ? jj : 0;
                        int r = __shfl(e.x, sel, 64);
                        float w = ok ? __int_as_float(__shfl(e.y, sel, 64)) : 0.f;
                        uint2 uu = hw2[(long)r * 32 + fl];
                        acc.x += w * __uint_as_float(uu.x << 16);
                        acc.y += w * __uint_as_float(uu.x & 0xffff0000u);
                        acc.z += w * __uint_as_float(uu.y << 16);
                        acc.w += w * __uint_as_float(uu.y & 0xffff0000u);
                    }
                }
            }
            acc.x += __shfl_xor(acc.x, 32, 64);
            acc.y += __shfl_xor(acc.y, 32, 64);
            acc.z += __shfl_xor(acc.z, 32, 64);
            acc.w += __shfl_xor(acc.w, 32, 64);
            float4 x = make_float4(fmaxf(acc.x, 0.f), fmaxf(acc.y, 0.f), fmaxf(acc.z, 0.f),
                                   fmaxf(acc.w, 0.f));
            if (half == 0) {
                xout[(long)node * 32 + fl] = x;
                if (STATS) {
                    s.x += x.x; s.y += x.y; s.z += x.z; s.w += x.w;
                    s2.x += x.x * x.x; s2.y += x.y * x.y;
                    s2.z += x.z * x.z; s2.w += x.w * x.w;
                }
            }
        }
    }
    if (STATS) {
        __shared__ float4 smS[256], smQ[256];
        smS[threadIdx.x] = s;
        smQ[threadIdx.x] = s2;
        __syncthreads();
        if (threadIdx.x < 32) {
            float4 a = smS[threadIdx.x], q = smQ[threadIdx.x];
#pragma unroll
            for (int w2 = 1; w2 < 4; ++w2) {
                float4 b = smS[w2 * 64 + threadIdx.x], c = smQ[w2 * 64 + threadIdx.x];
                a.x += b.x; a.y += b.y; a.z += b.z; a.w += b.w;
                q.x += c.x; q.y += c.y; q.z += c.z; q.w += c.w;
            }
            int f0 = 4 * threadIdx.x;
            pS[(f0 + 0) * NB + blockIdx.x] = a.x;
            pS[(f0 + 1) * NB + blockIdx.x] = a.y;
            pS[(f0 + 2) * NB + blockIdx.x] = a.z;
            pS[(f0 + 3) * NB + blockIdx.x] = a.w;
            pQ[(f0 + 0) * NB + blockIdx.x] = q.x;
            pQ[(f0 + 1) * NB + blockIdx.x] = q.y;
            pQ[(f0 + 2) * NB + blockIdx.x] = q.z;
            pQ[(f0 + 3) * NB + blockIdx.x] = q.w;
        }
    }
}

// ---------------- softmax pooling (bounds in-block, 1024 threads) ----------------

__global__ __launch_bounds__(1024) void pool_kernel(const float* __restrict__ tfidf,
                                                    const int* __restrict__ batch,
                                                    const float* __restrict__ x,
                                                    float* __restrict__ out, int n) {
    int g = blockIdx.x;
    int tid = threadIdx.x;
    __shared__ int sbounds[2];
    if (tid < 2) {
        int target = g + tid;
        int lo = 0, hi = n;
        while (lo < hi) {
            int mid = (lo + hi) >> 1;
            if (batch[mid] < target) lo = mid + 1;
            else hi = mid;
        }
        sbounds[tid] = lo;
    }
    __syncthreads();
    int s0 = sbounds[0], s1 = sbounds[1];
    int d = tid & 127, sub = tid >> 7;
    __shared__ float red[1024];
    float m = -1e30f;
    for (int i = s0 + tid; i < s1; i += 1024) m = fmaxf(m, tfidf[i]);
    red[tid] = m;
    __syncthreads();
    for (int off = 512; off > 0; off >>= 1) {
        if (tid < off) red[tid] = fmaxf(red[tid], red[tid + off]);
        __syncthreads();
    }
    m = red[0];
    __syncthreads();
    float s = 0.f;
    for (int i = s0 + tid; i < s1; i += 1024) s += __expf(tfidf[i] - m);
    red[tid] = s;
    __syncthreads();
    for (int off = 512; off > 0; off >>= 1) {
        if (tid < off) red[tid] += red[tid + off];
        __syncthreads();
    }
    s = red[0];
    __syncthreads();
    float acc = 0.f;
    for (int i = s0 + sub; i < s1; i += 8) acc += __expf(tfidf[i] - m) * x[(long)i * D + d];
    red[tid] = acc;
    __syncthreads();
    if (tid < 128) {
        float a = 0.f;
#pragma unroll
        for (int w = 0; w < 8; ++w) a += red[w * 128 + d];
        out[g * D + d] = (s1 > s0) ? a / s : 0.f;
    }
}

// ---------------- launch ----------------

extern "C" void kernel_launch(void* const* d_in, const int* in_sizes, int n_in, void* d_out,
                              int out_size, void* d_ws, size_t ws_size, hipStream_t stream) {
    const int N = in_sizes[0];
    const int E = in_sizes[4];
    const int G = out_size / D;
    const int BN_GRID = 768;
    const int AGG_GRID = 2048;

    const int* x_index = (const int*)d_in[0];
    const float* tfidf = (const float*)d_in[1];
    const int* ei_row = (const int*)d_in[2];
    const int* ei_col = ei_row + E;
    const int* batch = (const int*)d_in[3];
    const float* edge_attr = (const float*)d_in[4];
    const float* emb = (const float*)d_in[5];
    const float* gamma1 = (const float*)d_in[6];
    const float* beta1 = (const float*)d_in[7];
    const float* W1 = (const float*)d_in[8];
    const float* b1 = (const float*)d_in[9];
    const float* gamma2 = (const float*)d_in[10];
    const float* beta2 = (const float*)d_in[11];
    const float* W2 = (const float*)d_in[12];
    const float* b2 = (const float*)d_in[13];
    float* out = (float*)d_out;

    // ---- workspace carve (256B aligned) ----
    size_t off = 0;
    char* base = (char*)d_ws;
    auto carve = [&](size_t bytes) -> void* {
        void* p = base + off;
        off = (off + bytes + 255) & ~(size_t)255;
        return p;
    };
    unsigned short* bufA = (unsigned short*)carve((size_t)N * D * 2);  // h (bf16)
    float* bufB = (float*)carve((size_t)N * D * 4);                    // x (layer output)
    long long* pk = (long long*)carve((size_t)E * 8);                  // packed (row, ea)
    int2* csr = (int2*)carve((size_t)E * 8);                           // (row, ea) -> (row, w)
    int* rank = (int*)carve((size_t)E * 4);                            // arrival rank
    int* cnt = (int*)carve((size_t)N * 4);                             // zeroed each launch
    float* dis = (float*)carve((size_t)N * 4);
    int* offs = (int*)carve((size_t)(N + 1) * 4);
    int* bsum = (int*)carve(64 * 4);
    float* scale1 = (float*)carve(D * 4);
    float* shift1 = (float*)carve(D * 4);
    float* scale2 = (float*)carve(D * 4);
    float* shift2 = (float*)carve(D * 4);
    unsigned short* WT1b = (unsigned short*)carve((size_t)D * D * 2);
    unsigned short* WT2b = (unsigned short*)carve((size_t)D * D * 2);
    float* pS = (float*)carve((size_t)AGG_GRID * D * 4);
    float* pQ = (float*)carve((size_t)AGG_GRID * D * 4);
    (void)ws_size;
    (void)n_in;

    hipMemsetAsync(cnt, 0, (size_t)N * 4, stream);

    // ---- W -> bf16 transposed (both layers; no deps) ----
    prep_w<<<2 * D, D, 0, stream>>>(W1, W2, WT1b, WT2b);

    // ---- edge preprocessing: CSR (deterministic; shared by both layers) ----
    hist_rank_kernel<<<cdiv(E, 256), 256, 0, stream>>>(ei_col, cnt, rank, E);
    int nb = cdiv(N, 1024);
    scan_chunk_sums<<<nb, 1024, 0, stream>>>(cnt, bsum, N);
    scan_final<<<nb, 1024, 0, stream>>>(cnt, bsum, nb, offs, N, E);
    scatter_pack<<<cdiv(E, 256), 256, 0, stream>>>(ei_row, ei_col, edge_attr, rank, offs, pk,
                                                   E);
    sort_deg_kernel<<<cdiv(N, 4), 256, 0, stream>>>(pk, offs, dis, csr, N);
    fill_w_kernel<<<cdiv(N, 4), 256, 0, stream>>>(offs, dis, csr, N);

    // ---- layer 1 ----
    bn_stats<true><<<BN_GRID, 256, 0, stream>>>(emb, x_index, pS, pQ, N, BN_GRID);
    bn_reduce<<<D, 256, 0, stream>>>(pS, pQ, BN_GRID, gamma1, beta1, scale1, shift1, (float)N);
    gemm_mfma<true><<<cdiv(N, 64), 256, 0, stream>>>(emb, x_index, scale1, shift1, WT1b, bufA,
                                                     N);
    agg_kernel<true><<<AGG_GRID, 256, 0, stream>>>((const uint2*)bufA, csr, offs,
                                                   (const float4*)b1, (float4*)bufB, N, pS, pQ,
                                                   AGG_GRID);

    // ---- layer 2 ----
    bn_reduce<<<D, 256, 0, stream>>>(pS, pQ, AGG_GRID, gamma2, beta2, scale2, shift2, (float)N);
    gemm_mfma<false><<<cdiv(N, 64), 256, 0, stream>>>(bufB, nullptr, scale2, shift2, WT2b,
                                                      bufA, N);
    agg_kernel<false><<<cdiv(N, 4), 256, 0, stream>>>((const uint2*)bufA, csr, offs,
                                                      (const float4*)b2, (float4*)bufB, N,
                                                      nullptr, nullptr, 0);

    // ---- softmax pooling ----
    pool_kernel<<<G, 1024, 0, stream>>>(tfidf, batch, bufB, out, N);
}

// Round 15
// 283.889 us; speedup vs baseline: 2.7684x; 1.0465x over previous
//
#include <hip/hip_runtime.h>
#include <hip/hip_bf16.h>

#define D 128
#define EPSV 1e-5f

static inline int cdiv(int a, int b) { return (a + b - 1) / b; }

typedef __attribute__((ext_vector_type(8))) short short8v;
typedef __attribute__((ext_vector_type(4))) float floatx4;

// bf16 RNE pack / unpack helpers
__device__ __forceinline__ unsigned short f2bf(float f) {
    unsigned int x = __float_as_uint(f);
    unsigned int r = x + 0x7fffu + ((x >> 16) & 1u);
    return (unsigned short)(r >> 16);
}
__device__ __forceinline__ float bflo(unsigned int u) { return __uint_as_float(u << 16); }
__device__ __forceinline__ float bfhi(unsigned int u) {
    return __uint_as_float(u & 0xffff0000u);
}

// ---------------- W -> bf16 transposed + cnt zeroing (once per launch) ----------------

__global__ void prep_w(const float* __restrict__ W1, const float* __restrict__ W2,
                       unsigned short* __restrict__ WT1, unsigned short* __restrict__ WT2,
                       int* __restrict__ cnt, int N) {
    int b = blockIdx.x;
    const float* W = (b < D) ? W1 : W2;
    unsigned short* WT = (b < D) ? WT1 : WT2;
    int k = b & (D - 1);
    int n = threadIdx.x;
    WT[n * D + k] = f2bf(W[k * D + n]);
    int gid = b * D + n;
    for (int i = gid; i < N; i += 2 * D * D) cnt[i] = 0;
}

// ---------------- edge preprocessing (fully deterministic) ----------------
// hist also captures arrival rank (placement canonicalized later by sort).

__global__ void hist_rank_kernel(const int* __restrict__ col, int* __restrict__ cnt,
                                 int* __restrict__ rank, int E_) {
    int e = blockIdx.x * blockDim.x + threadIdx.x;
    if (e >= E_) return;
    rank[e] = atomicAdd(&cnt[col[e]], 1);
}

__global__ void scan_chunk_sums(const int* __restrict__ cnt, int* __restrict__ bsum, int n) {
    __shared__ int sm[1024];
    int i = blockIdx.x * 1024 + threadIdx.x;
    sm[threadIdx.x] = (i < n) ? cnt[i] : 0;
    __syncthreads();
    for (int off = 512; off > 0; off >>= 1) {
        if (threadIdx.x < off) sm[threadIdx.x] += sm[threadIdx.x + off];
        __syncthreads();
    }
    if (threadIdx.x == 0) bsum[blockIdx.x] = sm[0];
}

__global__ void scan_final(const int* __restrict__ cnt, const int* __restrict__ bsum, int nbk,
                           int* __restrict__ offs, int n, int E_) {
    __shared__ int sm[1024];
    __shared__ int sbo;
    int tid = threadIdx.x;
    int bv = (tid < nbk && tid < blockIdx.x) ? bsum[tid] : 0;
    sm[tid] = bv;
    __syncthreads();
    for (int off = 512; off > 0; off >>= 1) {
        if (tid < off) sm[tid] += sm[tid + off];
        __syncthreads();
    }
    if (tid == 0) {
        sbo = sm[0];
        if (blockIdx.x == 0) offs[n] = E_;
    }
    __syncthreads();
    int i = blockIdx.x * 1024 + tid;
    int v = (i < n) ? cnt[i] : 0;
    sm[tid] = v;
    __syncthreads();
    for (int off = 1; off < 1024; off <<= 1) {
        int t = (tid >= off) ? sm[tid - off] : 0;
        __syncthreads();
        sm[tid] += t;
        __syncthreads();
    }
    if (i < n) offs[i] = sm[tid] - v + sbo;
}

// scatter packed (src_row<<32 | ea_bits) into CSR slot offs[col]+rank.
__global__ void scatter_pack(const int* __restrict__ row, const int* __restrict__ col,
                             const float* __restrict__ ea, const int* __restrict__ rank,
                             const int* __restrict__ offs, long long* __restrict__ pk,
                             int E_) {
    int e = blockIdx.x * blockDim.x + threadIdx.x;
    if (e >= E_) return;
    int p = offs[col[e]] + rank[e];
    pk[p] = ((long long)row[e] << 32) | (unsigned int)__float_as_int(ea[e]);
}

// wave-level bitonic sort per node; key = (row, ea_bits); writes csr=(r,ea)
// (zero gathers); deterministic tree-sum of ea -> dis.
__global__ __launch_bounds__(256) void sort_deg_kernel(const long long* __restrict__ pk,
                                                       const int* __restrict__ offs,
                                                       float* __restrict__ dis,
                                                       int2* __restrict__ csr, int n) {
    int node = blockIdx.x * 4 + (threadIdx.x >> 6);
    int lane = threadIdx.x & 63;
    if (node >= n) return;
    int p0 = offs[node], p1 = offs[node + 1];
    int deg = p1 - p0;
    if (deg <= 64) {
        long long v = (lane < deg) ? pk[p0 + lane] : 0x7fffffffffffffffLL;
        for (int k = 2; k <= 64; k <<= 1) {
            for (int j = k >> 1; j > 0; j >>= 1) {
                long long partner = __shfl_xor(v, j, 64);
                bool up = ((lane & k) == 0);
                bool keepMin = ((lane & j) == 0);
                long long mn = v < partner ? v : partner;
                long long mx = v < partner ? partner : v;
                v = (up == keepMin) ? mn : mx;
            }
        }
        int r = (int)(v >> 32);
        int eab = (int)(v & 0xffffffffLL);
        if (lane < deg) csr[p0 + lane] = make_int2(r, eab);
        float av = (lane < deg) ? __int_as_float(eab) : 0.f;
        float s = av;
        for (int off = 32; off > 0; off >>= 1) s += __shfl_xor(s, off, 64);
        if (lane == 0) dis[node] = s > 0.f ? rsqrtf(fmaxf(s, EPSV)) : 0.f;
    } else {
        if (lane == 0) {  // deterministic O(d^2) selection fallback (unreachable)
            float dg = 0.f;
            for (int p = p0; p < p1; ++p) {
                long long best = 0x7fffffffffffffffLL;
                for (int q2 = p0; q2 < p1; ++q2) {
                    long long cand = pk[q2];
                    int less = 0;
                    for (int q3 = p0; q3 < p1; ++q3)
                        if (pk[q3] < cand) ++less;
                    if (less == p - p0) { best = cand; break; }
                }
                int r = (int)(best >> 32);
                int eab = (int)(best & 0xffffffffLL);
                csr[p] = make_int2(r, eab);
                dg += __int_as_float(eab);
            }
            dis[node] = dg > 0.f ? rsqrtf(fmaxf(dg, EPSV)) : 0.f;
        }
    }
}

// ---------------- batch norm stats (layer 1: emb gather) ----------------

template <bool GATHER>
__global__ __launch_bounds__(256) void bn_stats(const float* __restrict__ src,
                                                const int* __restrict__ idx,
                                                float* __restrict__ pS,
                                                float* __restrict__ pQ, int n, int NB) {
    int sub = threadIdx.x >> 5;
    int q = threadIdx.x & 31;
    float4 s = make_float4(0, 0, 0, 0), s2 = make_float4(0, 0, 0, 0);
    int stride = gridDim.x * 8;
    int i = blockIdx.x * 8 + sub;
    int r_next = (i < n) ? (GATHER ? idx[i] : i) : 0;
    for (; i < n; i += stride) {
        int r = r_next;
        int i2 = i + stride;
        if (i2 < n) r_next = GATHER ? idx[i2] : i2;
        float4 v = *(const float4*)&src[(long)r * D + q * 4];
        s.x += v.x; s.y += v.y; s.z += v.z; s.w += v.w;
        s2.x += v.x * v.x; s2.y += v.y * v.y; s2.z += v.z * v.z; s2.w += v.w * v.w;
    }
    __shared__ float4 redA[256], redB[256];
    redA[threadIdx.x] = s;
    redB[threadIdx.x] = s2;
    __syncthreads();
    for (int off = 128; off >= 32; off >>= 1) {
        if (threadIdx.x < off) {
            float4 a = redA[threadIdx.x + off], b = redB[threadIdx.x + off];
            redA[threadIdx.x].x += a.x; redA[threadIdx.x].y += a.y;
            redA[threadIdx.x].z += a.z; redA[threadIdx.x].w += a.w;
            redB[threadIdx.x].x += b.x; redB[threadIdx.x].y += b.y;
            redB[threadIdx.x].z += b.z; redB[threadIdx.x].w += b.w;
        }
        __syncthreads();
    }
    if (threadIdx.x < 32) {
        float4 a = redA[threadIdx.x], b = redB[threadIdx.x];
        int bofs = blockIdx.x;
        pS[(q * 4 + 0) * NB + bofs] = a.x;
        pS[(q * 4 + 1) * NB + bofs] = a.y;
        pS[(q * 4 + 2) * NB + bofs] = a.z;
        pS[(q * 4 + 3) * NB + bofs] = a.w;
        pQ[(q * 4 + 0) * NB + bofs] = b.x;
        pQ[(q * 4 + 1) * NB + bofs] = b.y;
        pQ[(q * 4 + 2) * NB + bofs] = b.z;
        pQ[(q * 4 + 3) * NB + bofs] = b.w;
    }
}

__global__ __launch_bounds__(256) void bn_reduce(const float* __restrict__ pS,
                                                 const float* __restrict__ pQ, int nb,
                                                 const float* __restrict__ gamma,
                                                 const float* __restrict__ beta,
                                                 float* __restrict__ scale,
                                                 float* __restrict__ shift, float n) {
    int d = blockIdx.x;
    int tid = threadIdx.x;
    float s = 0.f, q = 0.f;
    for (int b = tid; b < nb; b += 256) {
        s += pS[d * nb + b];
        q += pQ[d * nb + b];
    }
    __shared__ float smS[256], smQ[256];
    smS[tid] = s;
    smQ[tid] = q;
    __syncthreads();
    for (int off = 128; off > 0; off >>= 1) {
        if (tid < off) {
            smS[tid] += smS[tid + off];
            smQ[tid] += smQ[tid + off];
        }
        __syncthreads();
    }
    if (tid == 0) {
        float mean = smS[0] / n;
        float var = smQ[0] / n - mean * mean;
        float rstd = rsqrtf(var + EPSV);
        float sc = gamma[d] * rstd;
        scale[d] = sc;
        shift[d] = beta[d] - mean * sc;
    }
}

// ---------------- MFMA GEMM: h' = dis[r] * (bn(src) @ W), out bf16 ----------
// BF16IN: src is bf16 (layer-2 x); else fp32 with optional gather.

template <bool GATHER, bool BF16IN>
__global__ __launch_bounds__(256) void gemm_mfma(const void* __restrict__ srcv,
                                                 const int* __restrict__ idx,
                                                 const float* __restrict__ scale,
                                                 const float* __restrict__ shift,
                                                 const unsigned short* __restrict__ WTb,
                                                 const float* __restrict__ disv,
                                                 unsigned short* __restrict__ outb, int n) {
    __shared__ unsigned short xsb[64 * 136];   // 17.0 KB
    __shared__ unsigned short wsb[128 * 136];  // 34.0 KB (reused as float scratch in epi)
    int tid = threadIdx.x;
    int r0 = blockIdx.x * 64;
    const float4* scale4 = (const float4*)scale;
    const float4* shift4 = (const float4*)shift;
    for (int it = 0; it < 4; ++it) {
        int flat = it * 256 + tid;  // 0..1023
        int r = flat >> 4;
        int c16 = flat & 15;
        int gr = r0 + r;
        float4 v0 = make_float4(0, 0, 0, 0), v1 = make_float4(0, 0, 0, 0);
        if (gr < n) {
            int srow = GATHER ? idx[gr] : gr;
            float4 x0, x1;
            if (BF16IN) {
                const unsigned short* sb = (const unsigned short*)srcv;
                uint4 raw = *(const uint4*)&sb[(long)srow * D + c16 * 8];
                x0 = make_float4(bflo(raw.x), bfhi(raw.x), bflo(raw.y), bfhi(raw.y));
                x1 = make_float4(bflo(raw.z), bfhi(raw.z), bflo(raw.w), bfhi(raw.w));
            } else {
                const float* sf = (const float*)srcv;
                x0 = *(const float4*)&sf[(long)srow * D + c16 * 8];
                x1 = *(const float4*)&sf[(long)srow * D + c16 * 8 + 4];
            }
            float4 sa = scale4[c16 * 2], sb2 = shift4[c16 * 2];
            float4 sc = scale4[c16 * 2 + 1], sd = shift4[c16 * 2 + 1];
            v0 = make_float4(x0.x * sa.x + sb2.x, x0.y * sa.y + sb2.y, x0.z * sa.z + sb2.z,
                             x0.w * sa.w + sb2.w);
            v1 = make_float4(x1.x * sc.x + sd.x, x1.y * sc.y + sd.y, x1.z * sc.z + sd.z,
                             x1.w * sc.w + sd.w);
        }
        int phys = c16 ^ (r & 15);
        ushort4 o0 = make_ushort4(f2bf(v0.x), f2bf(v0.y), f2bf(v0.z), f2bf(v0.w));
        ushort4 o1 = make_ushort4(f2bf(v1.x), f2bf(v1.y), f2bf(v1.z), f2bf(v1.w));
        *(ushort4*)&xsb[r * 136 + phys * 8] = o0;
        *(ushort4*)&xsb[r * 136 + phys * 8 + 4] = o1;
    }
    for (int it = 0; it < 8; ++it) {
        int flat = it * 256 + tid;  // 0..2047
        int nrow = flat >> 4;
        int c16 = flat & 15;
        int phys = c16 ^ (nrow & 15);
        uint4 w = *(const uint4*)&WTb[nrow * D + c16 * 8];
        *(uint4*)&wsb[nrow * 136 + phys * 8] = w;
    }
    __syncthreads();
    int wv = tid >> 6;
    int lane = tid & 63;
    int m = lane & 15, q = lane >> 4;
    int r0w = wv * 16;
    floatx4 acc[8];
#pragma unroll
    for (int t = 0; t < 8; ++t) acc[t] = (floatx4)(0.f);
#pragma unroll
    for (int ks = 0; ks < 4; ++ks) {
        int c16 = ks * 4 + q;
        short8v a = *(short8v*)&xsb[(r0w + m) * 136 + (c16 ^ ((r0w + m) & 15)) * 8];
#pragma unroll
        for (int t = 0; t < 8; ++t) {
            short8v b = *(short8v*)&wsb[(t * 16 + m) * 136 + (c16 ^ m) * 8];
            acc[t] = __builtin_amdgcn_mfma_f32_16x16x32_bf16(a, b, acc[t], 0, 0, 0);
        }
    }
    __syncthreads();
    float* fl = (float*)wsb;  // 64 x 132 floats
#pragma unroll
    for (int t = 0; t < 8; ++t) {
#pragma unroll
        for (int r = 0; r < 4; ++r) {
            fl[(r0w + q * 4 + r) * 132 + t * 16 + m] = acc[t][r];
        }
    }
    __syncthreads();
    for (int it = 0; it < 4; ++it) {
        int c = it * 256 + tid;
        int r = c >> 4;
        int k8 = (c & 15) * 8;
        int gr = r0 + r;
        if (gr < n) {
            float dsc = disv[gr];  // fold dis[row] into h' (removes fill_w)
            float4 v0 = *(float4*)&fl[r * 132 + k8];
            float4 v1 = *(float4*)&fl[r * 132 + k8 + 4];
            ushort4 o0 = make_ushort4(f2bf(v0.x * dsc), f2bf(v0.y * dsc), f2bf(v0.z * dsc),
                                      f2bf(v0.w * dsc));
            ushort4 o1 = make_ushort4(f2bf(v1.x * dsc), f2bf(v1.y * dsc), f2bf(v1.z * dsc),
                                      f2bf(v1.w * dsc));
            *(ushort4*)&outb[(long)gr * D + k8] = o0;
            *(ushort4*)&outb[(long)gr * D + k8 + 4] = o1;
        }
    }
}

// ---------------- aggregation: dual-edge gathers ----------------
// x[c] = relu(b + dis[c] * sum_e ea_e * h'[row_e]); h' already has dis[row].
// STATS (layer 1): bf16 output + BN partials; else fp32 output.

template <bool STATS>
__global__ __launch_bounds__(256) void agg_kernel(const uint2* __restrict__ hw2,
                                                  const int2* __restrict__ csr,
                                                  const int* __restrict__ offs,
                                                  const float* __restrict__ dis,
                                                  const float4* __restrict__ bias4,
                                                  void* __restrict__ xoutv, int n,
                                                  float* __restrict__ pS,
                                                  float* __restrict__ pQ, int NB) {
    int lane = threadIdx.x & 63;
    int wv = threadIdx.x >> 6;
    int half = lane >> 5;
    int fl = lane & 31;
    float4 bs = bias4[fl];
    float4 s = make_float4(0.f, 0.f, 0.f, 0.f), s2 = make_float4(0.f, 0.f, 0.f, 0.f);
    int nGroups = (n + 3) >> 2;
    for (int grp = blockIdx.x; grp < nGroups; grp += gridDim.x) {
        int node = grp * 4 + wv;
        if (node < n) {
            int p0 = offs[node], p1 = offs[node + 1];
            float dc = dis[node];
            float4 acc = make_float4(0.f, 0.f, 0.f, 0.f);
            for (int base = p0; base < p1; base += 64) {
                int cnt = p1 - base;
                if (cnt > 64) cnt = 64;
                int2 e = csr[base + (lane < cnt ? lane : cnt - 1)];
                for (int j = 0; j < cnt; j += 8) {
#pragma unroll
                    for (int u = 0; u < 4; ++u) {
                        int jj = j + 2 * u + half;
                        bool ok = jj < cnt;
                        int sel = ok ? jj : 0;
                        int r = __shfl(e.x, sel, 64);
                        float w = ok ? __int_as_float(__shfl(e.y, sel, 64)) : 0.f;
                        uint2 uu = hw2[(long)r * 32 + fl];
                        acc.x += w * bflo(uu.x);
                        acc.y += w * bfhi(uu.x);
                        acc.z += w * bflo(uu.y);
                        acc.w += w * bfhi(uu.y);
                    }
                }
            }
            acc.x += __shfl_xor(acc.x, 32, 64);
            acc.y += __shfl_xor(acc.y, 32, 64);
            acc.z += __shfl_xor(acc.z, 32, 64);
            acc.w += __shfl_xor(acc.w, 32, 64);
            float4 x = make_float4(fmaxf(bs.x + dc * acc.x, 0.f), fmaxf(bs.y + dc * acc.y, 0.f),
                                   fmaxf(bs.z + dc * acc.z, 0.f),
                                   fmaxf(bs.w + dc * acc.w, 0.f));
            if (half == 0) {
                if (STATS) {
                    unsigned short* xb = (unsigned short*)xoutv;
                    ushort4 o = make_ushort4(f2bf(x.x), f2bf(x.y), f2bf(x.z), f2bf(x.w));
                    *(ushort4*)&xb[(long)node * D + fl * 4] = o;
                    s.x += x.x; s.y += x.y; s.z += x.z; s.w += x.w;
                    s2.x += x.x * x.x; s2.y += x.y * x.y;
                    s2.z += x.z * x.z; s2.w += x.w * x.w;
                } else {
                    ((float4*)xoutv)[(long)node * 32 + fl] = x;
                }
            }
        }
    }
    if (STATS) {
        __shared__ float4 smS[256], smQ[256];
        smS[threadIdx.x] = s;
        smQ[threadIdx.x] = s2;
        __syncthreads();
        if (threadIdx.x < 32) {
            float4 a = smS[threadIdx.x], q = smQ[threadIdx.x];
#pragma unroll
            for (int w2 = 1; w2 < 4; ++w2) {
                float4 b = smS[w2 * 64 + threadIdx.x], c = smQ[w2 * 64 + threadIdx.x];
                a.x += b.x; a.y += b.y; a.z += b.z; a.w += b.w;
                q.x += c.x; q.y += c.y; q.z += c.z; q.w += c.w;
            }
            int f0 = 4 * threadIdx.x;
            pS[(f0 + 0) * NB + blockIdx.x] = a.x;
            pS[(f0 + 1) * NB + blockIdx.x] = a.y;
            pS[(f0 + 2) * NB + blockIdx.x] = a.z;
            pS[(f0 + 3) * NB + blockIdx.x] = a.w;
            pQ[(f0 + 0) * NB + blockIdx.x] = q.x;
            pQ[(f0 + 1) * NB + blockIdx.x] = q.y;
            pQ[(f0 + 2) * NB + blockIdx.x] = q.z;
            pQ[(f0 + 3) * NB + blockIdx.x] = q.w;
        }
    }
}

// ---------------- softmax pooling (bounds in-block, 1024 threads) ----------------

__global__ __launch_bounds__(1024) void pool_kernel(const float* __restrict__ tfidf,
                                                    const int* __restrict__ batch,
                                                    const float* __restrict__ x,
                                                    float* __restrict__ out, int n) {
    int g = blockIdx.x;
    int tid = threadIdx.x;
    __shared__ int sbounds[2];
    if (tid < 2) {
        int target = g + tid;
        int lo = 0, hi = n;
        while (lo < hi) {
            int mid = (lo + hi) >> 1;
            if (batch[mid] < target) lo = mid + 1;
            else hi = mid;
        }
        sbounds[tid] = lo;
    }
    __syncthreads();
    int s0 = sbounds[0], s1 = sbounds[1];
    int d = tid & 127, sub = tid >> 7;
    __shared__ float red[1024];
    float m = -1e30f;
    for (int i = s0 + tid; i < s1; i += 1024) m = fmaxf(m, tfidf[i]);
    red[tid] = m;
    __syncthreads();
    for (int off = 512; off > 0; off >>= 1) {
        if (tid < off) red[tid] = fmaxf(red[tid], red[tid + off]);
        __syncthreads();
    }
    m = red[0];
    __syncthreads();
    float s = 0.f;
    for (int i = s0 + tid; i < s1; i += 1024) s += __expf(tfidf[i] - m);
    red[tid] = s;
    __syncthreads();
    for (int off = 512; off > 0; off >>= 1) {
        if (tid < off) red[tid] += red[tid + off];
        __syncthreads();
    }
    s = red[0];
    __syncthreads();
    float acc = 0.f;
    for (int i = s0 + sub; i < s1; i += 8) acc += __expf(tfidf[i] - m) * x[(long)i * D + d];
    red[tid] = acc;
    __syncthreads();
    if (tid < 128) {
        float a = 0.f;
#pragma unroll
        for (int w = 0; w < 8; ++w) a += red[w * 128 + d];
        out[g * D + d] = (s1 > s0) ? a / s : 0.f;
    }
}

// ---------------- launch ----------------

extern "C" void kernel_launch(void* const* d_in, const int* in_sizes, int n_in, void* d_out,
                              int out_size, void* d_ws, size_t ws_size, hipStream_t stream) {
    const int N = in_sizes[0];
    const int E = in_sizes[4];
    const int G = out_size / D;
    const int BN_GRID = 768;
    const int AGG_GRID = 2048;

    const int* x_index = (const int*)d_in[0];
    const float* tfidf = (const float*)d_in[1];
    const int* ei_row = (const int*)d_in[2];
    const int* ei_col = ei_row + E;
    const int* batch = (const int*)d_in[3];
    const float* edge_attr = (const float*)d_in[4];
    const float* emb = (const float*)d_in[5];
    const float* gamma1 = (const float*)d_in[6];
    const float* beta1 = (const float*)d_in[7];
    const float* W1 = (const float*)d_in[8];
    const float* b1 = (const float*)d_in[9];
    const float* gamma2 = (const float*)d_in[10];
    const float* beta2 = (const float*)d_in[11];
    const float* W2 = (const float*)d_in[12];
    const float* b2 = (const float*)d_in[13];
    float* out = (float*)d_out;

    // ---- workspace carve (256B aligned) ----
    size_t off = 0;
    char* base = (char*)d_ws;
    auto carve = [&](size_t bytes) -> void* {
        void* p = base + off;
        off = (off + bytes + 255) & ~(size_t)255;
        return p;
    };
    unsigned short* bufA = (unsigned short*)carve((size_t)N * D * 2);  // h' (bf16)
    float* bufB = (float*)carve((size_t)N * D * 4);  // x: bf16 (L1) / fp32 (L2)
    long long* pk = (long long*)carve((size_t)E * 8);  // packed (row, ea)
    int2* csr = (int2*)carve((size_t)E * 8);           // (row, ea)
    int* rank = (int*)carve((size_t)E * 4);            // arrival rank
    int* cnt = (int*)carve((size_t)N * 4);             // zeroed in prep_w
    float* dis = (float*)carve((size_t)N * 4);
    int* offs = (int*)carve((size_t)(N + 1) * 4);
    int* bsum = (int*)carve(64 * 4);
    float* scale1 = (float*)carve(D * 4);
    float* shift1 = (float*)carve(D * 4);
    float* scale2 = (float*)carve(D * 4);
    float* shift2 = (float*)carve(D * 4);
    unsigned short* WT1b = (unsigned short*)carve((size_t)D * D * 2);
    unsigned short* WT2b = (unsigned short*)carve((size_t)D * D * 2);
    float* pS = (float*)carve((size_t)AGG_GRID * D * 4);
    float* pQ = (float*)carve((size_t)AGG_GRID * D * 4);
    (void)ws_size;
    (void)n_in;

    // ---- W -> bf16 transposed + cnt zeroing ----
    prep_w<<<2 * D, D, 0, stream>>>(W1, W2, WT1b, WT2b, cnt, N);

    // ---- edge preprocessing: CSR (deterministic; shared by both layers) ----
    hist_rank_kernel<<<cdiv(E, 256), 256, 0, stream>>>(ei_col, cnt, rank, E);
    int nb = cdiv(N, 1024);
    scan_chunk_sums<<<nb, 1024, 0, stream>>>(cnt, bsum, N);
    scan_final<<<nb, 1024, 0, stream>>>(cnt, bsum, nb, offs, N, E);
    scatter_pack<<<cdiv(E, 256), 256, 0, stream>>>(ei_row, ei_col, edge_attr, rank, offs, pk,
                                                   E);
    sort_deg_kernel<<<cdiv(N, 4), 256, 0, stream>>>(pk, offs, dis, csr, N);

    // ---- layer 1 ----
    bn_stats<true><<<BN_GRID, 256, 0, stream>>>(emb, x_index, pS, pQ, N, BN_GRID);
    bn_reduce<<<D, 256, 0, stream>>>(pS, pQ, BN_GRID, gamma1, beta1, scale1, shift1, (float)N);
    gemm_mfma<true, false><<<cdiv(N, 64), 256, 0, stream>>>(emb, x_index, scale1, shift1, WT1b,
                                                            dis, bufA, N);
    agg_kernel<true><<<AGG_GRID, 256, 0, stream>>>((const uint2*)bufA, csr, offs, dis,
                                                   (const float4*)b1, bufB, N, pS, pQ,
                                                   AGG_GRID);

    // ---- layer 2 ----
    bn_reduce<<<D, 256, 0, stream>>>(pS, pQ, AGG_GRID, gamma2, beta2, scale2, shift2, (float)N);
    gemm_mfma<false, true><<<cdiv(N, 64), 256, 0, stream>>>(bufB, nullptr, scale2, shift2,
                                                            WT2b, dis, bufA, N);
    agg_kernel<false><<<cdiv(N, 4), 256, 0, stream>>>((const uint2*)bufA, csr, offs, dis,
                                                      (const float4*)b2, bufB, N, nullptr,
                                                      nullptr, 0);

    // ---- softmax pooling ----
    pool_kernel<<<G, 1024, 0, stream>>>(tfidf, batch, bufB, out, N);
}

// Round 16
// 278.855 us; speedup vs baseline: 2.8184x; 1.0181x over previous
//
#include <hip/hip_runtime.h>
#include <hip/hip_bf16.h>

#define D 128
#define EPSV 1e-5f

static inline int cdiv(int a, int b) { return (a + b - 1) / b; }

typedef __attribute__((ext_vector_type(8))) short short8v;
typedef __attribute__((ext_vector_type(4))) float floatx4;

// bf16 RNE pack / unpack helpers
__device__ __forceinline__ unsigned short f2bf(float f) {
    unsigned int x = __float_as_uint(f);
    unsigned int r = x + 0x7fffu + ((x >> 16) & 1u);
    return (unsigned short)(r >> 16);
}
__device__ __forceinline__ float bflo(unsigned int u) { return __uint_as_float(u << 16); }
__device__ __forceinline__ float bfhi(unsigned int u) {
    return __uint_as_float(u & 0xffff0000u);
}

// ---------------- W -> bf16 transposed + cnt zeroing (once per launch) ----------------

__global__ void prep_w(const float* __restrict__ W1, const float* __restrict__ W2,
                       unsigned short* __restrict__ WT1, unsigned short* __restrict__ WT2,
                       int* __restrict__ cnt, int N) {
    int b = blockIdx.x;
    const float* W = (b < D) ? W1 : W2;
    unsigned short* WT = (b < D) ? WT1 : WT2;
    int k = b & (D - 1);
    int n = threadIdx.x;
    WT[n * D + k] = f2bf(W[k * D + n]);
    int gid = b * D + n;
    for (int i = gid; i < N; i += 2 * D * D) cnt[i] = 0;
}

// ---------------- edge preprocessing (fully deterministic) ----------------

__global__ void hist_rank_kernel(const int* __restrict__ col, int* __restrict__ cnt,
                                 int* __restrict__ rank, int E_) {
    int e = blockIdx.x * blockDim.x + threadIdx.x;
    if (e >= E_) return;
    rank[e] = atomicAdd(&cnt[col[e]], 1);
}

__global__ void scan_chunk_sums(const int* __restrict__ cnt, int* __restrict__ bsum, int n) {
    __shared__ int sm[1024];
    int i = blockIdx.x * 1024 + threadIdx.x;
    sm[threadIdx.x] = (i < n) ? cnt[i] : 0;
    __syncthreads();
    for (int off = 512; off > 0; off >>= 1) {
        if (threadIdx.x < off) sm[threadIdx.x] += sm[threadIdx.x + off];
        __syncthreads();
    }
    if (threadIdx.x == 0) bsum[blockIdx.x] = sm[0];
}

__global__ void scan_final(const int* __restrict__ cnt, const int* __restrict__ bsum, int nbk,
                           int* __restrict__ offs, int n, int E_) {
    __shared__ int sm[1024];
    __shared__ int sbo;
    int tid = threadIdx.x;
    int bv = (tid < nbk && tid < blockIdx.x) ? bsum[tid] : 0;
    sm[tid] = bv;
    __syncthreads();
    for (int off = 512; off > 0; off >>= 1) {
        if (tid < off) sm[tid] += sm[tid + off];
        __syncthreads();
    }
    if (tid == 0) {
        sbo = sm[0];
        if (blockIdx.x == 0) offs[n] = E_;
    }
    __syncthreads();
    int i = blockIdx.x * 1024 + tid;
    int v = (i < n) ? cnt[i] : 0;
    sm[tid] = v;
    __syncthreads();
    for (int off = 1; off < 1024; off <<= 1) {
        int t = (tid >= off) ? sm[tid - off] : 0;
        __syncthreads();
        sm[tid] += t;
        __syncthreads();
    }
    if (i < n) offs[i] = sm[tid] - v + sbo;
}

// scatter packed (src_row<<32 | ea_bits) into CSR slot offs[col]+rank.
__global__ void scatter_pack(const int* __restrict__ row, const int* __restrict__ col,
                             const float* __restrict__ ea, const int* __restrict__ rank,
                             const int* __restrict__ offs, long long* __restrict__ pk,
                             int E_) {
    int e = blockIdx.x * blockDim.x + threadIdx.x;
    if (e >= E_) return;
    int p = offs[col[e]] + rank[e];
    pk[p] = ((long long)row[e] << 32) | (unsigned int)__float_as_int(ea[e]);
}

// wave-level bitonic sort per node; key = (row, ea_bits); writes csr=(r,ea)
// (zero gathers); deterministic tree-sum of ea -> dis.
__global__ __launch_bounds__(256) void sort_deg_kernel(const long long* __restrict__ pk,
                                                       const int* __restrict__ offs,
                                                       float* __restrict__ dis,
                                                       int2* __restrict__ csr, int n) {
    int node = blockIdx.x * 4 + (threadIdx.x >> 6);
    int lane = threadIdx.x & 63;
    if (node >= n) return;
    int p0 = offs[node], p1 = offs[node + 1];
    int deg = p1 - p0;
    if (deg <= 64) {
        long long v = (lane < deg) ? pk[p0 + lane] : 0x7fffffffffffffffLL;
        for (int k = 2; k <= 64; k <<= 1) {
            for (int j = k >> 1; j > 0; j >>= 1) {
                long long partner = __shfl_xor(v, j, 64);
                bool up = ((lane & k) == 0);
                bool keepMin = ((lane & j) == 0);
                long long mn = v < partner ? v : partner;
                long long mx = v < partner ? partner : v;
                v = (up == keepMin) ? mn : mx;
            }
        }
        int r = (int)(v >> 32);
        int eab = (int)(v & 0xffffffffLL);
        if (lane < deg) csr[p0 + lane] = make_int2(r, eab);
        float av = (lane < deg) ? __int_as_float(eab) : 0.f;
        float s = av;
        for (int off = 32; off > 0; off >>= 1) s += __shfl_xor(s, off, 64);
        if (lane == 0) dis[node] = s > 0.f ? rsqrtf(fmaxf(s, EPSV)) : 0.f;
    } else {
        if (lane == 0) {  // deterministic O(d^2) selection fallback (unreachable)
            float dg = 0.f;
            for (int p = p0; p < p1; ++p) {
                long long best = 0x7fffffffffffffffLL;
                for (int q2 = p0; q2 < p1; ++q2) {
                    long long cand = pk[q2];
                    int less = 0;
                    for (int q3 = p0; q3 < p1; ++q3)
                        if (pk[q3] < cand) ++less;
                    if (less == p - p0) { best = cand; break; }
                }
                int r = (int)(best >> 32);
                int eab = (int)(best & 0xffffffffLL);
                csr[p] = make_int2(r, eab);
                dg += __int_as_float(eab);
            }
            dis[node] = dg > 0.f ? rsqrtf(fmaxf(dg, EPSV)) : 0.f;
        }
    }
}

// ---------------- batch norm stats (layer 1: emb gather) ----------------

template <bool GATHER>
__global__ __launch_bounds__(256) void bn_stats(const float* __restrict__ src,
                                                const int* __restrict__ idx,
                                                float* __restrict__ pS,
                                                float* __restrict__ pQ, int n, int NB) {
    int sub = threadIdx.x >> 5;
    int q = threadIdx.x & 31;
    float4 s = make_float4(0, 0, 0, 0), s2 = make_float4(0, 0, 0, 0);
    int stride = gridDim.x * 8;
    int i = blockIdx.x * 8 + sub;
    int r_next = (i < n) ? (GATHER ? idx[i] : i) : 0;
    for (; i < n; i += stride) {
        int r = r_next;
        int i2 = i + stride;
        if (i2 < n) r_next = GATHER ? idx[i2] : i2;
        float4 v = *(const float4*)&src[(long)r * D + q * 4];
        s.x += v.x; s.y += v.y; s.z += v.z; s.w += v.w;
        s2.x += v.x * v.x; s2.y += v.y * v.y; s2.z += v.z * v.z; s2.w += v.w * v.w;
    }
    __shared__ float4 redA[256], redB[256];
    redA[threadIdx.x] = s;
    redB[threadIdx.x] = s2;
    __syncthreads();
    for (int off = 128; off >= 32; off >>= 1) {
        if (threadIdx.x < off) {
            float4 a = redA[threadIdx.x + off], b = redB[threadIdx.x + off];
            redA[threadIdx.x].x += a.x; redA[threadIdx.x].y += a.y;
            redA[threadIdx.x].z += a.z; redA[threadIdx.x].w += a.w;
            redB[threadIdx.x].x += b.x; redB[threadIdx.x].y += b.y;
            redB[threadIdx.x].z += b.z; redB[threadIdx.x].w += b.w;
        }
        __syncthreads();
    }
    if (threadIdx.x < 32) {
        float4 a = redA[threadIdx.x], b = redB[threadIdx.x];
        int bofs = blockIdx.x;
        pS[(q * 4 + 0) * NB + bofs] = a.x;
        pS[(q * 4 + 1) * NB + bofs] = a.y;
        pS[(q * 4 + 2) * NB + bofs] = a.z;
        pS[(q * 4 + 3) * NB + bofs] = a.w;
        pQ[(q * 4 + 0) * NB + bofs] = b.x;
        pQ[(q * 4 + 1) * NB + bofs] = b.y;
        pQ[(q * 4 + 2) * NB + bofs] = b.z;
        pQ[(q * 4 + 3) * NB + bofs] = b.w;
    }
}

__global__ __launch_bounds__(256) void bn_reduce(const float* __restrict__ pS,
                                                 const float* __restrict__ pQ, int nb,
                                                 const float* __restrict__ gamma,
                                                 const float* __restrict__ beta,
                                                 float* __restrict__ scale,
                                                 float* __restrict__ shift, float n) {
    int d = blockIdx.x;
    int tid = threadIdx.x;
    float s = 0.f, q = 0.f;
    for (int b = tid; b < nb; b += 256) {
        s += pS[d * nb + b];
        q += pQ[d * nb + b];
    }
    __shared__ float smS[256], smQ[256];
    smS[tid] = s;
    smQ[tid] = q;
    __syncthreads();
    for (int off = 128; off > 0; off >>= 1) {
        if (tid < off) {
            smS[tid] += smS[tid + off];
            smQ[tid] += smQ[tid + off];
        }
        __syncthreads();
    }
    if (tid == 0) {
        float mean = smS[0] / n;
        float var = smQ[0] / n - mean * mean;
        float rstd = rsqrtf(var + EPSV);
        float sc = gamma[d] * rstd;
        scale[d] = sc;
        shift[d] = beta[d] - mean * sc;
    }
}

// ---------------- MFMA GEMM: h' = dis[r] * (bn(src) @ W), out bf16 ----------

template <bool GATHER, bool BF16IN>
__global__ __launch_bounds__(256) void gemm_mfma(const void* __restrict__ srcv,
                                                 const int* __restrict__ idx,
                                                 const float* __restrict__ scale,
                                                 const float* __restrict__ shift,
                                                 const unsigned short* __restrict__ WTb,
                                                 const float* __restrict__ disv,
                                                 unsigned short* __restrict__ outb, int n) {
    __shared__ unsigned short xsb[64 * 136];   // 17.0 KB
    __shared__ unsigned short wsb[128 * 136];  // 34.0 KB (reused as float scratch in epi)
    int tid = threadIdx.x;
    int r0 = blockIdx.x * 64;
    const float4* scale4 = (const float4*)scale;
    const float4* shift4 = (const float4*)shift;
    for (int it = 0; it < 4; ++it) {
        int flat = it * 256 + tid;  // 0..1023
        int r = flat >> 4;
        int c16 = flat & 15;
        int gr = r0 + r;
        float4 v0 = make_float4(0, 0, 0, 0), v1 = make_float4(0, 0, 0, 0);
        if (gr < n) {
            int srow = GATHER ? idx[gr] : gr;
            float4 x0, x1;
            if (BF16IN) {
                const unsigned short* sb = (const unsigned short*)srcv;
                uint4 raw = *(const uint4*)&sb[(long)srow * D + c16 * 8];
                x0 = make_float4(bflo(raw.x), bfhi(raw.x), bflo(raw.y), bfhi(raw.y));
                x1 = make_float4(bflo(raw.z), bfhi(raw.z), bflo(raw.w), bfhi(raw.w));
            } else {
                const float* sf = (const float*)srcv;
                x0 = *(const float4*)&sf[(long)srow * D + c16 * 8];
                x1 = *(const float4*)&sf[(long)srow * D + c16 * 8 + 4];
            }
            float4 sa = scale4[c16 * 2], sb2 = shift4[c16 * 2];
            float4 sc = scale4[c16 * 2 + 1], sd = shift4[c16 * 2 + 1];
            v0 = make_float4(x0.x * sa.x + sb2.x, x0.y * sa.y + sb2.y, x0.z * sa.z + sb2.z,
                             x0.w * sa.w + sb2.w);
            v1 = make_float4(x1.x * sc.x + sd.x, x1.y * sc.y + sd.y, x1.z * sc.z + sd.z,
                             x1.w * sc.w + sd.w);
        }
        int phys = c16 ^ (r & 15);
        ushort4 o0 = make_ushort4(f2bf(v0.x), f2bf(v0.y), f2bf(v0.z), f2bf(v0.w));
        ushort4 o1 = make_ushort4(f2bf(v1.x), f2bf(v1.y), f2bf(v1.z), f2bf(v1.w));
        *(ushort4*)&xsb[r * 136 + phys * 8] = o0;
        *(ushort4*)&xsb[r * 136 + phys * 8 + 4] = o1;
    }
    for (int it = 0; it < 8; ++it) {
        int flat = it * 256 + tid;  // 0..2047
        int nrow = flat >> 4;
        int c16 = flat & 15;
        int phys = c16 ^ (nrow & 15);
        uint4 w = *(const uint4*)&WTb[nrow * D + c16 * 8];
        *(uint4*)&wsb[nrow * 136 + phys * 8] = w;
    }
    __syncthreads();
    int wv = tid >> 6;
    int lane = tid & 63;
    int m = lane & 15, q = lane >> 4;
    int r0w = wv * 16;
    floatx4 acc[8];
#pragma unroll
    for (int t = 0; t < 8; ++t) acc[t] = (floatx4)(0.f);
#pragma unroll
    for (int ks = 0; ks < 4; ++ks) {
        int c16 = ks * 4 + q;
        short8v a = *(short8v*)&xsb[(r0w + m) * 136 + (c16 ^ ((r0w + m) & 15)) * 8];
#pragma unroll
        for (int t = 0; t < 8; ++t) {
            short8v b = *(short8v*)&wsb[(t * 16 + m) * 136 + (c16 ^ m) * 8];
            acc[t] = __builtin_amdgcn_mfma_f32_16x16x32_bf16(a, b, acc[t], 0, 0, 0);
        }
    }
    __syncthreads();
    float* fl = (float*)wsb;  // 64 x 132 floats
#pragma unroll
    for (int t = 0; t < 8; ++t) {
#pragma unroll
        for (int r = 0; r < 4; ++r) {
            fl[(r0w + q * 4 + r) * 132 + t * 16 + m] = acc[t][r];
        }
    }
    __syncthreads();
    for (int it = 0; it < 4; ++it) {
        int c = it * 256 + tid;
        int r = c >> 4;
        int k8 = (c & 15) * 8;
        int gr = r0 + r;
        if (gr < n) {
            float dsc = disv[gr];  // fold dis[row] into h' (removes fill_w)
            float4 v0 = *(float4*)&fl[r * 132 + k8];
            float4 v1 = *(float4*)&fl[r * 132 + k8 + 4];
            ushort4 o0 = make_ushort4(f2bf(v0.x * dsc), f2bf(v0.y * dsc), f2bf(v0.z * dsc),
                                      f2bf(v0.w * dsc));
            ushort4 o1 = make_ushort4(f2bf(v1.x * dsc), f2bf(v1.y * dsc), f2bf(v1.z * dsc),
                                      f2bf(v1.w * dsc));
            *(ushort4*)&outb[(long)gr * D + k8] = o0;
            *(ushort4*)&outb[(long)gr * D + k8 + 4] = o1;
        }
    }
}

// ---------------- aggregation: dual-edge gathers ----------------
// x[c] = relu(b + dis[c] * sum_e ea_e * h'[row_e]); output bf16 (both layers).
// STATS (layer 1) additionally accumulates BN partials.

template <bool STATS>
__global__ __launch_bounds__(256) void agg_kernel(const uint2* __restrict__ hw2,
                                                  const int2* __restrict__ csr,
                                                  const int* __restrict__ offs,
                                                  const float* __restrict__ dis,
                                                  const float4* __restrict__ bias4,
                                                  unsigned short* __restrict__ xoutb, int n,
                                                  float* __restrict__ pS,
                                                  float* __restrict__ pQ, int NB) {
    int lane = threadIdx.x & 63;
    int wv = threadIdx.x >> 6;
    int half = lane >> 5;
    int fl = lane & 31;
    float4 bs = bias4[fl];
    float4 s = make_float4(0.f, 0.f, 0.f, 0.f), s2 = make_float4(0.f, 0.f, 0.f, 0.f);
    int nGroups = (n + 3) >> 2;
    for (int grp = blockIdx.x; grp < nGroups; grp += gridDim.x) {
        int node = grp * 4 + wv;
        if (node < n) {
            int p0 = offs[node], p1 = offs[node + 1];
            float dc = dis[node];
            float4 acc = make_float4(0.f, 0.f, 0.f, 0.f);
            for (int base = p0; base < p1; base += 64) {
                int cnt = p1 - base;
                if (cnt > 64) cnt = 64;
                int2 e = csr[base + (lane < cnt ? lane : cnt - 1)];
                for (int j = 0; j < cnt; j += 8) {
#pragma unroll
                    for (int u = 0; u < 4; ++u) {
                        int jj = j + 2 * u + half;
                        bool ok = jj < cnt;
                        int sel = ok ? jj : 0;
                        int r = __shfl(e.x, sel, 64);
                        float w = ok ? __int_as_float(__shfl(e.y, sel, 64)) : 0.f;
                        uint2 uu = hw2[(long)r * 32 + fl];
                        acc.x += w * bflo(uu.x);
                        acc.y += w * bfhi(uu.x);
                        acc.z += w * bflo(uu.y);
                        acc.w += w * bfhi(uu.y);
                    }
                }
            }
            acc.x += __shfl_xor(acc.x, 32, 64);
            acc.y += __shfl_xor(acc.y, 32, 64);
            acc.z += __shfl_xor(acc.z, 32, 64);
            acc.w += __shfl_xor(acc.w, 32, 64);
            float4 x = make_float4(fmaxf(bs.x + dc * acc.x, 0.f), fmaxf(bs.y + dc * acc.y, 0.f),
                                   fmaxf(bs.z + dc * acc.z, 0.f),
                                   fmaxf(bs.w + dc * acc.w, 0.f));
            if (half == 0) {
                ushort4 o = make_ushort4(f2bf(x.x), f2bf(x.y), f2bf(x.z), f2bf(x.w));
                *(ushort4*)&xoutb[(long)node * D + fl * 4] = o;
                if (STATS) {
                    s.x += x.x; s.y += x.y; s.z += x.z; s.w += x.w;
                    s2.x += x.x * x.x; s2.y += x.y * x.y;
                    s2.z += x.z * x.z; s2.w += x.w * x.w;
                }
            }
        }
    }
    if (STATS) {
        __shared__ float4 smS[256], smQ[256];
        smS[threadIdx.x] = s;
        smQ[threadIdx.x] = s2;
        __syncthreads();
        if (threadIdx.x < 32) {
            float4 a = smS[threadIdx.x], q = smQ[threadIdx.x];
#pragma unroll
            for (int w2 = 1; w2 < 4; ++w2) {
                float4 b = smS[w2 * 64 + threadIdx.x], c = smQ[w2 * 64 + threadIdx.x];
                a.x += b.x; a.y += b.y; a.z += b.z; a.w += b.w;
                q.x += c.x; q.y += c.y; q.z += c.z; q.w += c.w;
            }
            int f0 = 4 * threadIdx.x;
            pS[(f0 + 0) * NB + blockIdx.x] = a.x;
            pS[(f0 + 1) * NB + blockIdx.x] = a.y;
            pS[(f0 + 2) * NB + blockIdx.x] = a.z;
            pS[(f0 + 3) * NB + blockIdx.x] = a.w;
            pQ[(f0 + 0) * NB + blockIdx.x] = q.x;
            pQ[(f0 + 1) * NB + blockIdx.x] = q.y;
            pQ[(f0 + 2) * NB + blockIdx.x] = q.z;
            pQ[(f0 + 3) * NB + blockIdx.x] = q.w;
        }
    }
}

// ---------------- softmax pooling (bounds in-block; bf16 x input) ----------------

__global__ __launch_bounds__(1024) void pool_kernel(const float* __restrict__ tfidf,
                                                    const int* __restrict__ batch,
                                                    const unsigned short* __restrict__ xb,
                                                    float* __restrict__ out, int n) {
    int g = blockIdx.x;
    int tid = threadIdx.x;
    __shared__ int sbounds[2];
    if (tid < 2) {
        int target = g + tid;
        int lo = 0, hi = n;
        while (lo < hi) {
            int mid = (lo + hi) >> 1;
            if (batch[mid] < target) lo = mid + 1;
            else hi = mid;
        }
        sbounds[tid] = lo;
    }
    __syncthreads();
    int s0 = sbounds[0], s1 = sbounds[1];
    int d = tid & 127, sub = tid >> 7;
    __shared__ float red[1024];
    float m = -1e30f;
    for (int i = s0 + tid; i < s1; i += 1024) m = fmaxf(m, tfidf[i]);
    red[tid] = m;
    __syncthreads();
    for (int off = 512; off > 0; off >>= 1) {
        if (tid < off) red[tid] = fmaxf(red[tid], red[tid + off]);
        __syncthreads();
    }
    m = red[0];
    __syncthreads();
    float s = 0.f;
    for (int i = s0 + tid; i < s1; i += 1024) s += __expf(tfidf[i] - m);
    red[tid] = s;
    __syncthreads();
    for (int off = 512; off > 0; off >>= 1) {
        if (tid < off) red[tid] += red[tid + off];
        __syncthreads();
    }
    s = red[0];
    __syncthreads();
    float acc = 0.f;
    for (int i = s0 + sub; i < s1; i += 8) {
        float xv = __uint_as_float(((unsigned int)xb[(long)i * D + d]) << 16);
        acc += __expf(tfidf[i] - m) * xv;
    }
    red[tid] = acc;
    __syncthreads();
    if (tid < 128) {
        float a = 0.f;
#pragma unroll
        for (int w = 0; w < 8; ++w) a += red[w * 128 + d];
        out[g * D + d] = (s1 > s0) ? a / s : 0.f;
    }
}

// ---------------- launch ----------------

extern "C" void kernel_launch(void* const* d_in, const int* in_sizes, int n_in, void* d_out,
                              int out_size, void* d_ws, size_t ws_size, hipStream_t stream) {
    const int N = in_sizes[0];
    const int E = in_sizes[4];
    const int G = out_size / D;
    const int BN_GRID = 768;
    const int AGG_GRID = 2048;

    const int* x_index = (const int*)d_in[0];
    const float* tfidf = (const float*)d_in[1];
    const int* ei_row = (const int*)d_in[2];
    const int* ei_col = ei_row + E;
    const int* batch = (const int*)d_in[3];
    const float* edge_attr = (const float*)d_in[4];
    const float* emb = (const float*)d_in[5];
    const float* gamma1 = (const float*)d_in[6];
    const float* beta1 = (const float*)d_in[7];
    const float* W1 = (const float*)d_in[8];
    const float* b1 = (const float*)d_in[9];
    const float* gamma2 = (const float*)d_in[10];
    const float* beta2 = (const float*)d_in[11];
    const float* W2 = (const float*)d_in[12];
    const float* b2 = (const float*)d_in[13];
    float* out = (float*)d_out;

    // ---- workspace carve (256B aligned) ----
    size_t off = 0;
    char* base = (char*)d_ws;
    auto carve = [&](size_t bytes) -> void* {
        void* p = base + off;
        off = (off + bytes + 255) & ~(size_t)255;
        return p;
    };
    unsigned short* bufA = (unsigned short*)carve((size_t)N * D * 2);  // h' (bf16)
    unsigned short* bufB = (unsigned short*)carve((size_t)N * D * 2);  // x (bf16)
    long long* pk = (long long*)carve((size_t)E * 8);                  // packed (row, ea)
    int2* csr = (int2*)carve((size_t)E * 8);                           // (row, ea)
    int* rank = (int*)carve((size_t)E * 4);                            // arrival rank
    int* cnt = (int*)carve((size_t)N * 4);                             // zeroed in prep_w
    float* dis = (float*)carve((size_t)N * 4);
    int* offs = (int*)carve((size_t)(N + 1) * 4);
    int* bsum = (int*)carve(64 * 4);
    float* scale1 = (float*)carve(D * 4);
    float* shift1 = (float*)carve(D * 4);
    float* scale2 = (float*)carve(D * 4);
    float* shift2 = (float*)carve(D * 4);
    unsigned short* WT1b = (unsigned short*)carve((size_t)D * D * 2);
    unsigned short* WT2b = (unsigned short*)carve((size_t)D * D * 2);
    float* pS = (float*)carve((size_t)AGG_GRID * D * 4);
    float* pQ = (float*)carve((size_t)AGG_GRID * D * 4);
    (void)ws_size;
    (void)n_in;

    // ---- W -> bf16 transposed + cnt zeroing ----
    prep_w<<<2 * D, D, 0, stream>>>(W1, W2, WT1b, WT2b, cnt, N);

    // ---- edge preprocessing: CSR (deterministic; shared by both layers) ----
    hist_rank_kernel<<<cdiv(E, 256), 256, 0, stream>>>(ei_col, cnt, rank, E);
    int nb = cdiv(N, 1024);
    scan_chunk_sums<<<nb, 1024, 0, stream>>>(cnt, bsum, N);
    scan_final<<<nb, 1024, 0, stream>>>(cnt, bsum, nb, offs, N, E);
    scatter_pack<<<cdiv(E, 256), 256, 0, stream>>>(ei_row, ei_col, edge_attr, rank, offs, pk,
                                                   E);
    sort_deg_kernel<<<cdiv(N, 4), 256, 0, stream>>>(pk, offs, dis, csr, N);

    // ---- layer 1 ----
    bn_stats<true><<<BN_GRID, 256, 0, stream>>>(emb, x_index, pS, pQ, N, BN_GRID);
    bn_reduce<<<D, 256, 0, stream>>>(pS, pQ, BN_GRID, gamma1, beta1, scale1, shift1, (float)N);
    gemm_mfma<true, false><<<cdiv(N, 64), 256, 0, stream>>>(emb, x_index, scale1, shift1, WT1b,
                                                            dis, bufA, N);
    agg_kernel<true><<<AGG_GRID, 256, 0, stream>>>((const uint2*)bufA, csr, offs, dis,
                                                   (const float4*)b1, bufB, N, pS, pQ,
                                                   AGG_GRID);

    // ---- layer 2 ----
    bn_reduce<<<D, 256, 0, stream>>>(pS, pQ, AGG_GRID, gamma2, beta2, scale2, shift2, (float)N);
    gemm_mfma<false, true><<<cdiv(N, 64), 256, 0, stream>>>(bufB, nullptr, scale2, shift2,
                                                            WT2b, dis, bufA, N);
    agg_kernel<false><<<cdiv(N, 4), 256, 0, stream>>>((const uint2*)bufA, csr, offs, dis,
                                                      (const float4*)b2, bufB, N, nullptr,
                                                      nullptr, 0);

    // ---- softmax pooling (bf16 x) ----
    pool_kernel<<<G, 1024, 0, stream>>>(tfidf, batch, bufB, out, N);
}